// Round 2
// baseline (1483.429 us; speedup 1.0000x reference)
//
#include <hip/hip_runtime.h>
#include <cstdint>
#include <cstddef>

// ---------------------------------------------------------------------------
// B=16 V=30522 D=512 H=8 DH=64 FF=2048 NC=4 NF=30 NN=34 FL=64 HL=32 L=2
// INPUT float tensors may be fp32 OR bf16 -- detected at runtime from ln1_g
// (all 1.0): fp32 -> first u32 == 0x3F800000 ; bf16 -> 0x3F803F80.
// OUTPUT: 65 FLOAT32 values = [loss, final_pred(16x4)].
// R10 change vs R9 (passed, 1191.2 us): replace the 128x128 2-barrier GEMM
// (819 TF on FF1, ~91% of the m97-structure ~900 TF ceiling) with the 256x256
// 8-phase counted-vmcnt template (T3+T4+T5, m201): 8 waves (2Mx4N), BK=64,
// 128 KiB LDS = 2 bufs x {A,B} x 2 halves (interleaved 64-row stripes).
// Per phase: {ds_read frag subtile | stage 1 half-tile (2x global_load_lds) |
// s_waitcnt vmcnt(6) | barrier | setprio(1) 16 MFMA setprio(0) | barrier}.
// Stage order per tile: A0(t+1)@p0, B1(t+1)@p1, B0(t+2)@p2, A1(t+2)@p3 --
// uniform 2 loads/phase makes vmcnt(6) an exact 3-half-tile-in-flight bound;
// tail CLAMPS the staged tile (dead-slot writes) so counting stays exact.
// Keeps R8 chunk-rotation LDS swizzle (0 bank conflicts) + R9 XCD swizzle.
// Predicted: FF1 78.7 -> ~48 us, MfmaUtil 35 -> ~58%; total ~1000 us.
// ---------------------------------------------------------------------------

using u16 = unsigned short;

typedef __bf16 bf16x8 __attribute__((ext_vector_type(8)));
typedef float  floatx4 __attribute__((ext_vector_type(4)));

#if defined(__has_builtin)
#if __has_builtin(__builtin_amdgcn_global_load_lds)
#define USE_GLL 1
#endif
#endif

__device__ __forceinline__ float bf2f(u16 u) {
  return __uint_as_float(((unsigned)u) << 16);
}
__device__ __forceinline__ u16 f2bf(float f) {
  unsigned u = __float_as_uint(f);
  u += 0x7FFFu + ((u >> 16) & 1u);   // round-to-nearest-even
  return (u16)(u >> 16);
}
__device__ __forceinline__ float ldf(const void* p, size_t i, int isb) {
  return isb ? bf2f(((const u16*)p)[i]) : ((const float*)p)[i];
}

__device__ __forceinline__ float waveSum(float v) {
#pragma unroll
  for (int o = 32; o > 0; o >>= 1) v += __shfl_xor(v, o, 64);
  return v;
}
__device__ __forceinline__ float waveMax(float v) {
#pragma unroll
  for (int o = 32; o > 0; o >>= 1) v = fmaxf(v, __shfl_xor(v, o, 64));
  return v;
}
__device__ __forceinline__ float blockSum(float v, float* sh4) {
  v = waveSum(v);
  if ((threadIdx.x & 63) == 0) sh4[threadIdx.x >> 6] = v;
  __syncthreads();
  float r = sh4[0] + sh4[1] + sh4[2] + sh4[3];
  __syncthreads();
  return r;
}
__device__ __forceinline__ float blockMax(float v, float* sh4) {
  v = waveMax(v);
  if ((threadIdx.x & 63) == 0) sh4[threadIdx.x >> 6] = v;
  __syncthreads();
  float r = fmaxf(fmaxf(sh4[0], sh4[1]), fmaxf(sh4[2], sh4[3]));
  __syncthreads();
  return r;
}

// ---------------------------------------------------------------------------
__global__ void detect_kernel(const void* __restrict__ ln1g, int* __restrict__ flag) {
  unsigned u = *(const unsigned*)ln1g;
  *flag = (u == 0x3F800000u) ? 0 : 1;
}

// ---------------------------------------------------------------------------
// Transpose + ->bf16: src elements [eoff + k*N + n] -> dst[n*K + k].
// ---------------------------------------------------------------------------
__global__ __launch_bounds__(256) void transpose_kernel(const void* __restrict__ src,
                                                        u16* __restrict__ dst,
                                                        int K, int N, size_t eoff,
                                                        const int* __restrict__ F) {
  const int isb = *F;
  __shared__ u16 tile[32][33];
  int bx = blockIdx.x, by = blockIdx.y;
  int tx = threadIdx.x & 31, ty = threadIdx.x >> 5;
  for (int i = ty; i < 32; i += 8)
    tile[i][tx] = f2bf(ldf(src, eoff + (size_t)(by * 32 + i) * N + bx * 32 + tx, isb));
  __syncthreads();
  for (int i = ty; i < 32; i += 8)
    dst[(size_t)(bx * 32 + i) * K + by * 32 + tx] = tile[tx][i];
}

// ---------------------------------------------------------------------------
// Embedding + positional encoding. One block per token.
// ---------------------------------------------------------------------------
__global__ __launch_bounds__(256) void embed_kernel(const int* __restrict__ ids,
                                                    const void* __restrict__ emb,
                                                    u16* __restrict__ x, int L,
                                                    const int* __restrict__ F) {
  const int isb = *F;
  int tok = blockIdx.x;
  int pos = tok % L;
  int id = ids[tok];
  const float LOG1E4_OVER_D = 9.210340371976184f / 512.0f;
  for (int d = threadIdx.x; d < 512; d += 256) {
    float e = ldf(emb, (size_t)id * 512 + d, isb) * 22.62741699796952f;
    int i2 = d & ~1;
    float ang = (float)pos * expf(-(float)i2 * LOG1E4_OVER_D);
    float pe = (d & 1) ? cosf(ang) : sinf(ang);
    x[(size_t)tok * 512 + d] = f2bf(e + pe);
  }
}

// ---------------------------------------------------------------------------
// 256x256 8-phase GEMM: C[M][N] = A[M][K] @ Bt[N][K]^T + bias  (optional relu)
// 512 threads = 8 waves (2M x 4N); per-wave C = 128x64 = acc[8][4] floatx4.
// LDS halves (16 KB each): A-half h = tile rows with ((r>>6)&1)==h (stripes
// h, h+2); B-half n = Bt rows with ((r>>5)&1)==n. Local row within a half:
// A: lr = (r&63) + ((r>>7)<<6); B: lr = (r&31) + ((r>>6)<<5).
// Rows store eight 16B chunks ROTATED by local row (R8 swizzle): global
// chunk q at position (q+lr)&7 -- staged via rotated GLOBAL source chunk so
// global_load_lds dests stay lane-contiguous; ds_reads are conflict-free.
// ---------------------------------------------------------------------------
#define GLL16(GP, LP) __builtin_amdgcn_global_load_lds( \
    (const __attribute__((address_space(1))) void*)(GP), \
    (__attribute__((address_space(3))) void*)(LP), 16, 0, 0)

template <int RELU>
__global__ __launch_bounds__(512, 2) void gemm256(const u16* __restrict__ A,
                                                  const u16* __restrict__ Bt,
                                                  const void* __restrict__ bias,
                                                  u16* __restrict__ C,
                                                  int M, int N, int K, size_t boff,
                                                  const int* __restrict__ F) {
  const int isb = *F;
  __shared__ __align__(16) u16 As[2][2][128 * 64];
  __shared__ __align__(16) u16 Bs[2][2][128 * 64];
  const int tid = threadIdx.x;
  const int lane = tid & 63;
  const int wave = tid >> 6;          // 0..7
  const int wm = wave >> 2;           // 0..1 (M)
  const int wnn = wave & 3;           // 0..3 (N)
  const int l15 = lane & 15, quad = lane >> 4;

  // XCD-aware bijective remap (T1, m192/m204), bn fastest per XCD chunk.
  const int nwg = gridDim.x * gridDim.y;
  const int hw = blockIdx.y * gridDim.x + blockIdx.x;
  int lg;
  if ((nwg & 7) == 0) {
    lg = (hw & 7) * (nwg >> 3) + (hw >> 3);
  } else {
    int q = nwg >> 3, r = nwg & 7, xcd = hw & 7, j = hw >> 3;
    lg = (xcd < r ? xcd * (q + 1) : r * (q + 1) + (xcd - r) * q) + j;
  }
  const int bm = lg / gridDim.x;
  const int bn = lg - bm * gridDim.x;

  const u16* Abase = A + (size_t)bm * 256 * K;
  const u16* Bbase = Bt + (size_t)bn * 256 * K;

  // Staging per-thread invariants: chunk c=tid (sweep0) and c=512+tid
  // (sweep1, local row +64 -> global row +128, same rotated column).
  const int slr = tid >> 3;                 // local row 0..63 (sweep0)
  const int sp = tid & 7;                   // chunk position 0..7
  const int colrot = ((sp - slr) & 7) * 8;  // rotated source column (elems)
  const int rowB0 = (slr & 31) + ((slr >> 5) << 6);  // B-half global row (n=0)
  const int nt = K >> 6;

#define STAGE_A(H, T, BUF) { \
    const u16* g_ = Abase + (size_t)((H) * 64 + slr) * K + (T) * 64 + colrot; \
    u16* d_ = &As[(BUF)][(H)][tid * 8]; \
    GLL16(g_, d_); \
    GLL16(g_ + (size_t)128 * K, d_ + 4096); }

#define STAGE_B(NH, T, BUF) { \
    const u16* g_ = Bbase + (size_t)((NH) * 32 + rowB0) * K + (T) * 64 + colrot; \
    u16* d_ = &Bs[(BUF)][(NH)][tid * 8]; \
    GLL16(g_, d_); \
    GLL16(g_ + (size_t)128 * K, d_ + 4096); }

#define LOADAF(MH, BUF) { \
    _Pragma("unroll") for (int ks = 0; ks < 2; ks++) \
    _Pragma("unroll") for (int mi = 0; mi < 4; mi++) { \
      int r_ = wm * 64 + mi * 16 + l15; \
      int q_ = ks * 4 + quad; \
      af[ks][mi] = *(const bf16x8*)&As[(BUF)][(MH)][r_ * 64 + ((q_ + r_) & 7) * 8]; } }

#define LOADBF(NH, BUF) { \
    _Pragma("unroll") for (int ks = 0; ks < 2; ks++) \
    _Pragma("unroll") for (int ni = 0; ni < 2; ni++) { \
      int r_ = wnn * 32 + ni * 16 + l15; \
      int q_ = ks * 4 + quad; \
      bfr[ks][ni] = *(const bf16x8*)&Bs[(BUF)][(NH)][r_ * 64 + ((q_ + r_) & 7) * 8]; } }

#define MFMAQ(MH, NH) { \
    __builtin_amdgcn_s_setprio(1); \
    _Pragma("unroll") for (int ks = 0; ks < 2; ks++) \
    _Pragma("unroll") for (int mi = 0; mi < 4; mi++) \
    _Pragma("unroll") for (int ni = 0; ni < 2; ni++) \
      acc[(MH) * 4 + mi][(NH) * 2 + ni] = __builtin_amdgcn_mfma_f32_16x16x32_bf16( \
          af[ks][mi], bfr[ks][ni], acc[(MH) * 4 + mi][(NH) * 2 + ni], 0, 0, 0); \
    __builtin_amdgcn_s_setprio(0); }

#define WAITV6 asm volatile("s_waitcnt vmcnt(6)" ::: "memory")
#define BAR __builtin_amdgcn_s_barrier()

  floatx4 acc[8][4];
#pragma unroll
  for (int i = 0; i < 8; i++)
#pragma unroll
    for (int j = 0; j < 4; j++) acc[i][j] = (floatx4){0.f, 0.f, 0.f, 0.f};

  bf16x8 af[2][4], bfr[2][2];

  // Prologue (issue order matters for vmcnt counting):
  // B0(0), A1(0), A0(0), B1(0), B0(1), A1(1); vmcnt(4) confirms tile 0.
  {
    const int t1 = (nt > 1) ? 1 : 0;
    STAGE_B(0, 0, 0);
    STAGE_A(1, 0, 0);
    STAGE_A(0, 0, 0);
    STAGE_B(1, 0, 0);
    STAGE_B(0, t1, 1);
    STAGE_A(1, t1, 1);
    asm volatile("s_waitcnt vmcnt(4)" ::: "memory");
    BAR;
  }

  for (int t = 0; t < nt; ++t) {
    const int cur = t & 1;
    const int ta = (t + 1 < nt) ? t + 1 : nt - 1;  // clamp: dead-slot dummies
    const int tb = (t + 2 < nt) ? t + 2 : nt - 1;  // keep vmcnt count exact
    // phase 0: quadrant (m0,n0)
    LOADAF(0, cur);
    LOADBF(0, cur);
    STAGE_A(0, ta, cur ^ 1);
    WAITV6; BAR;
    MFMAQ(0, 0);
    BAR;
    // phase 1: quadrant (m1,n0) -- reuse B0 frags
    LOADAF(1, cur);
    STAGE_B(1, ta, cur ^ 1);
    WAITV6; BAR;
    MFMAQ(1, 0);
    BAR;
    // phase 2: quadrant (m1,n1) -- reuse A1 frags
    LOADBF(1, cur);
    STAGE_B(0, tb, cur);
    WAITV6; BAR;
    MFMAQ(1, 1);
    BAR;
    // phase 3: quadrant (m0,n1) -- reuse B1 frags
    LOADAF(0, cur);
    STAGE_A(1, tb, cur);
    WAITV6; BAR;
    MFMAQ(0, 1);
    BAR;
  }

#pragma unroll
  for (int an = 0; an < 4; an++) {
    int gcol = bn * 256 + wnn * 64 + (an >> 1) * 32 + (an & 1) * 16 + l15;
    float bv = ldf(bias, boff + gcol, isb);
#pragma unroll
    for (int am = 0; am < 8; am++) {
      int growb = bm * 256 + wm * 128 + (am >> 2) * 64 + (am & 3) * 16 + quad * 4;
#pragma unroll
      for (int r = 0; r < 4; r++) {
        float v = acc[am][an][r] + bv;
        if (RELU) v = fmaxf(v, 0.f);
        C[(size_t)(growb + r) * N + gcol] = f2bf(v);
      }
    }
  }
#undef STAGE_A
#undef STAGE_B
#undef LOADAF
#undef LOADBF
#undef MFMAQ
#undef WAITV6
#undef BAR
}

// ---------------------------------------------------------------------------
// MFMA attention: one block per (seq, head), 256 threads (2x2 wave grid).
// LDS row stride 72 elems (144 B) -> fragment reads are 2-way (free).
// ---------------------------------------------------------------------------
__global__ __launch_bounds__(256) void attn_kernel(const u16* __restrict__ qkv,
                                                   u16* __restrict__ o, int L) {
  const int h = blockIdx.x & 7;
  const int s = blockIdx.x >> 3;
  __shared__ __align__(16) u16 Qs[64 * 72];   // Q, later reused as P
  __shared__ __align__(16) u16 Ks[64 * 72];
  __shared__ __align__(16) u16 Vt[64 * 72];   // V^T: [d][t]
  __shared__ float Ss[64 * 66];
  const int tid = threadIdx.x;
  const int lane = tid & 63;
  const int wave = tid >> 6;
  const int wm = wave >> 1, wn = wave & 1;
  const int l15 = lane & 15, quad = lane >> 4;
  const int base = s * L;

  for (int idx = tid; idx < 512; idx += 256) {
    int t = idx >> 3, d8 = (idx & 7) * 8;
    if (t < L) {
      size_t g = (size_t)(base + t) * 1536 + h * 64 + d8;
      *(uint4*)&Qs[t * 72 + d8] = *(const uint4*)&qkv[g];
      *(uint4*)&Ks[t * 72 + d8] = *(const uint4*)&qkv[g + 512];
      u16 vv[8];
      *(uint4*)vv = *(const uint4*)&qkv[g + 1024];
#pragma unroll
      for (int i = 0; i < 8; i++) Vt[(d8 + i) * 72 + t] = vv[i];
    } else {
      uint4 z = {0u, 0u, 0u, 0u};
      *(uint4*)&Qs[t * 72 + d8] = z;
      *(uint4*)&Ks[t * 72 + d8] = z;
#pragma unroll
      for (int i = 0; i < 8; i++) Vt[(d8 + i) * 72 + t] = 0;
    }
  }
  __syncthreads();

  {
    floatx4 acc[2][2];
#pragma unroll
    for (int mi = 0; mi < 2; mi++)
#pragma unroll
      for (int ni = 0; ni < 2; ni++) acc[mi][ni] = (floatx4){0.f, 0.f, 0.f, 0.f};
#pragma unroll
    for (int ks = 0; ks < 2; ks++) {
      bf16x8 af[2], bfr[2];
#pragma unroll
      for (int mi = 0; mi < 2; mi++)
        af[mi] = *(const bf16x8*)&Qs[(wm * 32 + mi * 16 + l15) * 72 + ks * 32 + quad * 8];
#pragma unroll
      for (int ni = 0; ni < 2; ni++)
        bfr[ni] = *(const bf16x8*)&Ks[(wn * 32 + ni * 16 + l15) * 72 + ks * 32 + quad * 8];
#pragma unroll
      for (int mi = 0; mi < 2; mi++)
#pragma unroll
        for (int ni = 0; ni < 2; ni++)
          acc[mi][ni] = __builtin_amdgcn_mfma_f32_16x16x32_bf16(af[mi], bfr[ni], acc[mi][ni], 0, 0, 0);
    }
#pragma unroll
    for (int mi = 0; mi < 2; mi++)
#pragma unroll
      for (int ni = 0; ni < 2; ni++)
#pragma unroll
        for (int r = 0; r < 4; r++)
          Ss[(wm * 32 + mi * 16 + quad * 4 + r) * 66 + wn * 32 + ni * 16 + l15] =
              acc[mi][ni][r] * 0.125f;
  }
  __syncthreads();

  {
    int r = tid >> 2, sub = tid & 3;
    int j0 = sub * 16;
    float mx = -3.4e38f;
    if (r < L)
      for (int j = j0; j < j0 + 16; j++)
        if (j < L) mx = fmaxf(mx, Ss[r * 66 + j]);
    mx = fmaxf(mx, __shfl_xor(mx, 1, 64));
    mx = fmaxf(mx, __shfl_xor(mx, 2, 64));
    float sum = 0.f;
    if (r < L)
      for (int j = j0; j < j0 + 16; j++)
        if (j < L) sum += expf(Ss[r * 66 + j] - mx);
    sum += __shfl_xor(sum, 1, 64);
    sum += __shfl_xor(sum, 2, 64);
    float inv = 1.f / sum;
    if (r < L)
      for (int j = j0; j < j0 + 16; j++)
        Qs[r * 72 + j] = (j < L) ? f2bf(expf(Ss[r * 66 + j] - mx) * inv) : (u16)0;
  }
  __syncthreads();

  {
    floatx4 acc[2][2];
#pragma unroll
    for (int mi = 0; mi < 2; mi++)
#pragma unroll
      for (int ni = 0; ni < 2; ni++) acc[mi][ni] = (floatx4){0.f, 0.f, 0.f, 0.f};
#pragma unroll
    for (int ks = 0; ks < 2; ks++) {
      bf16x8 af[2], bfr[2];
#pragma unroll
      for (int mi = 0; mi < 2; mi++)
        af[mi] = *(const bf16x8*)&Qs[(wm * 32 + mi * 16 + l15) * 72 + ks * 32 + quad * 8];
#pragma unroll
      for (int ni = 0; ni < 2; ni++)
        bfr[ni] = *(const bf16x8*)&Vt[(wn * 32 + ni * 16 + l15) * 72 + ks * 32 + quad * 8];
#pragma unroll
      for (int mi = 0; mi < 2; mi++)
#pragma unroll
        for (int ni = 0; ni < 2; ni++)
          acc[mi][ni] = __builtin_amdgcn_mfma_f32_16x16x32_bf16(af[mi], bfr[ni], acc[mi][ni], 0, 0, 0);
    }
#pragma unroll
    for (int mi = 0; mi < 2; mi++) {
#pragma unroll
      for (int r = 0; r < 4; r++) {
        int t = wm * 32 + mi * 16 + quad * 4 + r;
        if (t < L) {
#pragma unroll
          for (int ni = 0; ni < 2; ni++) {
            int d = wn * 32 + ni * 16 + l15;
            o[(size_t)(base + t) * 512 + h * 64 + d] = f2bf(acc[mi][ni][r]);
          }
        }
      }
    }
  }
}

// ---------------------------------------------------------------------------
// x = LayerNorm(x + y) * g[eoff..] + b[eoff..]
// ---------------------------------------------------------------------------
__global__ __launch_bounds__(256) void add_ln_kernel(u16* __restrict__ x,
                                                     const u16* __restrict__ y,
                                                     const void* __restrict__ g,
                                                     const void* __restrict__ b,
                                                     size_t eoff,
                                                     const int* __restrict__ F) {
  const int isb = *F;
  const int row = blockIdx.x, tid = threadIdx.x;
  __shared__ float sh[4];
  size_t o0 = (size_t)row * 512 + tid;
  float v0 = bf2f(x[o0]) + bf2f(y[o0]);
  float v1 = bf2f(x[o0 + 256]) + bf2f(y[o0 + 256]);
  float mean = blockSum(v0 + v1, sh) * (1.f / 512.f);
  float d0 = v0 - mean, d1 = v1 - mean;
  float var = blockSum(d0 * d0 + d1 * d1, sh) * (1.f / 512.f);
  float rstd = rsqrtf(var + 1e-5f);
  x[o0]       = f2bf(d0 * rstd * ldf(g, eoff + tid, isb)       + ldf(b, eoff + tid, isb));
  x[o0 + 256] = f2bf(d1 * rstd * ldf(g, eoff + tid + 256, isb) + ldf(b, eoff + tid + 256, isb));
}

// ---------------------------------------------------------------------------
// Masked mean pool; mask elements at [moff + s*L + t].
// ---------------------------------------------------------------------------
__global__ __launch_bounds__(256) void pool_kernel(const u16* __restrict__ x,
                                                   const void* __restrict__ mask,
                                                   float* __restrict__ pooled, int L,
                                                   size_t moff,
                                                   const int* __restrict__ F) {
  const int isb = *F;
  const int s = blockIdx.x;
  float msum = 0.f;
  for (int t = 0; t < L; t++) msum += ldf(mask, moff + s * L + t, isb);
  float inv = 1.f / fmaxf(msum, 1e-9f);
  for (int d = threadIdx.x; d < 512; d += 256) {
    float acc = 0.f;
    for (int t = 0; t < L; t++)
      acc += bf2f(x[(size_t)(s * L + t) * 512 + d]) * ldf(mask, moff + s * L + t, isb);
    pooled[(size_t)s * 512 + d] = acc * inv;
  }
}

// ---------------------------------------------------------------------------
// Pairwise score
// ---------------------------------------------------------------------------
__global__ __launch_bounds__(64) void pair_score_kernel(const float* __restrict__ X,
                                                        const float* __restrict__ Y,
                                                        const void* __restrict__ Wv,
                                                        const void* __restrict__ bscal,
                                                        float* __restrict__ outp,
                                                        int NI, int NJ,
                                                        const int* __restrict__ F) {
  const int isb = *F;
  int gid = blockIdx.x;
  int j = gid % NJ;
  int t = gid / NJ;
  int i = t % NI;
  int b = t / NI;
  const float* xv = X + ((size_t)b * NI + i) * 512;
  const float* yv = Y + ((size_t)b * NJ + j) * 512;
  int l = threadIdx.x;
  float p = 0.f;
  for (int d = l; d < 512; d += 64) {
    float xi = xv[d], yj = yv[d];
    p += ldf(Wv, d, isb) * yj + ldf(Wv, 512 + d, isb) * xi +
         ldf(Wv, 1024 + d, isb) * fabsf(yj - xi) + ldf(Wv, 1536 + d, isb) * xi * yj;
  }
  p = waveSum(p);
  if (l == 0) outp[gid] = p + ldf(bscal, 0, isb);
}

__global__ __launch_bounds__(256) void aa_softmax_kernel(const float* __restrict__ aa,
                                                         float* __restrict__ aasm) {
  const int b = blockIdx.x;
  const float* src = aa + (size_t)b * 900;
  float* dst = aasm + (size_t)b * 900;
  __shared__ float sh[4];
  int tid = threadIdx.x;
  float mx = -3.4e38f;
  for (int i = tid; i < 900; i += 256) mx = fmaxf(mx, src[i]);
  mx = blockMax(mx, sh);
  float sum = 0.f;
  for (int i = tid; i < 900; i += 256) sum += expf(src[i] - mx);
  sum = blockSum(sum, sh);
  float inv = 1.f / sum;
  for (int i = tid; i < 900; i += 256) {
    int r = i / 30, c = i - r * 30;
    dst[i] = (r == c) ? 0.f : expf(src[i] - mx) * inv;
  }
}

__global__ __launch_bounds__(64) void qa_softmax_kernel(const float* __restrict__ qa,
                                                        float* __restrict__ sim) {
  int g = blockIdx.x;
  int l = threadIdx.x;
  float v = (l < 30) ? qa[(size_t)g * 30 + l] : -3.4e38f;
  float mx = waveMax(v);
  float e = (l < 30) ? expf(v - mx) : 0.f;
  float s = waveSum(e);
  if (l < 30) sim[(size_t)g * 30 + l] = e / s;
}

// ---------------------------------------------------------------------------
// Edge weights
// ---------------------------------------------------------------------------
__global__ __launch_bounds__(256) void edgew_kernel(const void* __restrict__ aaov,
                                                    const void* __restrict__ aasim_in,
                                                    const void* __restrict__ qaov,
                                                    const void* __restrict__ qq,
                                                    const float* __restrict__ aasm,
                                                    const float* __restrict__ sim,
                                                    const void* __restrict__ p1,
                                                    const void* __restrict__ p2,
                                                    const void* __restrict__ p3,
                                                    const void* __restrict__ p4,
                                                    float* __restrict__ Wout,
                                                    const int* __restrict__ F) {
  const int isb = *F;
  int e = blockIdx.x * 256 + threadIdx.x;
  if (e >= 16 * 1156) return;
  int b = e / 1156;
  int rem = e - b * 1156;
  int r = rem / 34, c = rem - r * 34;
  float aas;
  if (r >= 4 && c >= 4) aas = aasm[(size_t)b * 900 + (r - 4) * 30 + (c - 4)];
  else                  aas = ldf(aasim_in, e, isb);
  float qas = 0.f;
  if (r >= 4 && c < 4)      qas = sim[((size_t)b * 4 + c) * 30 + (r - 4)];
  else if (r < 4 && c >= 4) qas = sim[((size_t)b * 4 + r) * 30 + (c - 4)];
  float w = -ldf(p1, 0, isb) * ldf(aaov, e, isb) + ldf(p2, 0, isb) * aas +
            ldf(p3, 0, isb) * ldf(qaov, e, isb) + ldf(p4, 0, isb) * qas +
            ldf(qq, e, isb);
  Wout[e] = w;
}

// ---------------------------------------------------------------------------
// Projected gradient ascent (100 iters), register-resident, barrier-free.
// ---------------------------------------------------------------------------
__global__ __launch_bounds__(64) void solve_kernel(const float* __restrict__ Wmat,
                                                   float* __restrict__ pred,
                                                   float* __restrict__ outp) {
  const int b = blockIdx.x;
  const int lane = threadIdx.x;
  float E[19], Ws[19], As[19];
  bool dg[19];
#pragma unroll
  for (int k = 0; k < 19; k++) {
    int e = lane + (k << 6);
    if (e < 1156) {
      int r = e / 34, c = e - r * 34;
      float w1 = Wmat[(size_t)b * 1156 + e];
      float w2 = Wmat[(size_t)b * 1156 + c * 34 + r];
      Ws[k] = 0.5f * (w1 + w2);
      As[k] = 0.5f * (((w1 != 0.f) ? 1.f : 0.f) + ((w2 != 0.f) ? 1.f : 0.f));
      dg[k] = (r == c && r < 4);
      E[k] = 0.5f;
    } else {
      Ws[k] = 0.f; As[k] = 0.f; dg[k] = false; E[k] = 0.f;
    }
  }
  for (int it = 0; it < 100; it++) {
    float ps = 0.f;
#pragma unroll
    for (int k = 0; k < 19; k++) ps += As[k] * E[k];
    float s = waveSum(ps);
    float dd = __shfl(E[0], 0, 64) + __shfl(E[0], 35, 64) +
               __shfl(E[1], 6, 64) + __shfl(E[1], 41, 64);
    float coef_s = (s > 6.f) ? 20.f * (s - 6.f) : 0.f;
    float coef_d = 20.f * (dd - 1.f);
#pragma unroll
    for (int k = 0; k < 19; k++) {
      float g = Ws[k] - coef_s * As[k] - (dg[k] ? coef_d : 0.f);
      E[k] = fminf(fmaxf(E[k] + 0.05f * g, 0.f), 1.f);
    }
  }
  float v0 = E[0], v1 = E[1];
  if (lane == 0)  { pred[b * 4 + 0] = v0; outp[1 + b * 4 + 0] = v0; }
  if (lane == 35) { pred[b * 4 + 1] = v0; outp[1 + b * 4 + 1] = v0; }
  if (lane == 6)  { pred[b * 4 + 2] = v1; outp[1 + b * 4 + 2] = v1; }
  if (lane == 41) { pred[b * 4 + 3] = v1; outp[1 + b * 4 + 3] = v1; }
}

// ---------------------------------------------------------------------------
// Final loss: out[0] = ce(log_softmax(pred), labels) + mse(sim, gold_sm)
// ---------------------------------------------------------------------------
__global__ __launch_bounds__(256) void loss_kernel(const float* __restrict__ sim,
                                                   const void* __restrict__ gold,
                                                   const float* __restrict__ pred,
                                                   const int* __restrict__ labels,
                                                   float* __restrict__ outp,
                                                   const int* __restrict__ F) {
  const int isb = *F;
  __shared__ float sh[4];
  const int tid = threadIdx.x;
  float local = 0.f;
  if (tid < 64) {
    float mx = -3.4e38f;
    for (int k = 0; k < 30; k++) mx = fmaxf(mx, ldf(gold, (size_t)tid * 30 + k, isb));
    float sum = 0.f;
    for (int k = 0; k < 30; k++) sum += expf(ldf(gold, (size_t)tid * 30 + k, isb) - mx);
    float inv = 1.f / sum;
    for (int k = 0; k < 30; k++) {
      float gsm = expf(ldf(gold, (size_t)tid * 30 + k, isb) - mx) * inv;
      float d = sim[(size_t)tid * 30 + k] - gsm;
      local += d * d;
    }
  }
  float mse = blockSum(local, sh) * (1.f / 1920.f);
  float cel = 0.f;
  if (tid < 16) {
    const float* f = pred + tid * 4;
    int lb = labels[tid] & 3;
    float mx = fmaxf(fmaxf(f[0], f[1]), fmaxf(f[2], f[3]));
    float lse = logf(expf(f[0] - mx) + expf(f[1] - mx) + expf(f[2] - mx) + expf(f[3] - mx));
    float lp = f[lb] - mx - lse;
    cel = -lp * (1.f / 16.f);
  }
  float ce = blockSum(cel, sh);
  if (tid == 0) outp[0] = ce + mse;
}

// ---------------------------------------------------------------------------
// Host orchestration
// ---------------------------------------------------------------------------
extern "C" void kernel_launch(void* const* d_in, const int* in_sizes, int n_in,
                              void* d_out, int out_size, void* d_ws, size_t ws_size,
                              hipStream_t stream) {
  (void)in_sizes; (void)n_in; (void)out_size;
  const int*  hyp_ids   = (const int*)d_in[0];
  const void* hyp_mask  = d_in[1];
  const void* fact_mask = d_in[2];
  const int*  fact_ids  = (const int*)d_in[3];
  const void* aa_ov     = d_in[5];
  const void* aa_sim_in = d_in[6];
  const void* qa_ov     = d_in[8];
  const void* qq        = d_in[11];
  const int*  labels    = (const int*)d_in[12];
  const void* gold      = d_in[13];
  const void* emb       = d_in[14];
  const void* Wqkv      = d_in[15];
  const void* bqkv      = d_in[16];
  const void* Wo        = d_in[17];
  const void* bo        = d_in[18];
  const void* ln1g      = d_in[19];
  const void* ln1b      = d_in[20];
  const void* Wff1      = d_in[21];
  const void* bff1      = d_in[22];
  const void* Wff2      = d_in[23];
  const void* bff2      = d_in[24];
  const void* ln2g      = d_in[25];
  const void* ln2b      = d_in[26];
  const void* scoreW    = d_in[27];
  const void* scoreB    = d_in[28];
  const void* absW      = d_in[29];
  const void* absB      = d_in[30];
  const void* p_aaov    = d_in[31];
  const void* p_aasim   = d_in[32];
  const void* p_qaov    = d_in[33];
  const void* p_qasim   = d_in[34];
  float* out = (float*)d_out;

  char* ws = (char*)d_ws;
  size_t off = 0;
  auto alloc = [&](size_t bytes) -> void* {
    void* p = ws + off;
    off += (bytes + 255) & ~(size_t)255;
    return p;
  };

  float* PRED = (float*)alloc(64ull * 4);
  int*   FLAG = (int*)alloc(256);
  float* SIM  = (float*)alloc(16ull * 120 * 4);
  float* QA   = (float*)alloc(16ull * 120 * 4);
  float* AASM = (float*)alloc(16ull * 900 * 4);
  float* AA   = (float*)alloc(16ull * 900 * 4);
  float* WMAT = (float*)alloc(16ull * 1156 * 4);
  float* FSEQ = (float*)alloc(480ull * 512 * 4);
  float* HSEQ = (float*)alloc(64ull * 512 * 4);
  u16* WT_QKV = (u16*)alloc(2ull * 1536 * 512 * 2);
  u16* WT_O   = (u16*)alloc(2ull * 512 * 512 * 2);
  u16* WT_F1  = (u16*)alloc(2ull * 2048 * 512 * 2);
  u16* WT_F2  = (u16*)alloc(2ull * 512 * 2048 * 2);

  // Dynamic chunking from ws_size (constant per process -> graph-safe).
  // All chunk sizes are multiples of 256 tokens (gemm256 tile constraint).
  const int opts_tok[5] = {30720, 15360, 10240, 6144, 3072};
  const int opts_nch[5] = {1, 2, 3, 5, 10};
  int CH_TOK = 3072, NCH = 10;
  for (int i = 0; i < 5; i++) {
    size_t need = off + (size_t)opts_tok[i] * 7168 + 4096;
    if (need <= ws_size) { CH_TOK = opts_tok[i]; NCH = opts_nch[i]; break; }
  }
  u16* X   = (u16*)alloc((size_t)CH_TOK * 512 * 2);
  u16* BIG = (u16*)alloc((size_t)CH_TOK * 2048 * 2);
  u16* ATT = (u16*)alloc((size_t)CH_TOK * 512 * 2);
  u16* Y   = (u16*)alloc((size_t)CH_TOK * 512 * 2);

  detect_kernel<<<1, 1, 0, stream>>>(ln1g, FLAG);

  for (int l = 0; l < 2; l++) {
    transpose_kernel<<<dim3(48, 16), 256, 0, stream>>>(
        Wqkv, WT_QKV + (size_t)l * 1536 * 512, 512, 1536, (size_t)l * 512 * 1536, FLAG);
    transpose_kernel<<<dim3(16, 16), 256, 0, stream>>>(
        Wo, WT_O + (size_t)l * 512 * 512, 512, 512, (size_t)l * 512 * 512, FLAG);
    transpose_kernel<<<dim3(64, 16), 256, 0, stream>>>(
        Wff1, WT_F1 + (size_t)l * 2048 * 512, 512, 2048, (size_t)l * 512 * 2048, FLAG);
    transpose_kernel<<<dim3(16, 64), 256, 0, stream>>>(
        Wff2, WT_F2 + (size_t)l * 512 * 2048, 2048, 512, (size_t)l * 2048 * 512, FLAG);
  }

  auto encode = [&](const int* ids, int nseq, int L, const void* mask,
                    size_t moff, float* pooled) {
    int M = nseq * L;   // multiple of 256
    embed_kernel<<<M, 256, 0, stream>>>(ids, emb, X, L, FLAG);
    for (int l = 0; l < 2; l++) {
      gemm256<0><<<dim3(6, M / 256), 512, 0, stream>>>(
          X, WT_QKV + (size_t)l * 1536 * 512, bqkv, BIG, M, 1536, 512,
          (size_t)l * 1536, FLAG);
      attn_kernel<<<nseq * 8, 256, 0, stream>>>(BIG, ATT, L);
      gemm256<0><<<dim3(2, M / 256), 512, 0, stream>>>(
          ATT, WT_O + (size_t)l * 512 * 512, bo, Y, M, 512, 512,
          (size_t)l * 512, FLAG);
      add_ln_kernel<<<M, 256, 0, stream>>>(X, Y, ln1g, ln1b, (size_t)l * 512, FLAG);
      gemm256<1><<<dim3(8, M / 256), 512, 0, stream>>>(
          X, WT_F1 + (size_t)l * 2048 * 512, bff1, BIG, M, 2048, 512,
          (size_t)l * 2048, FLAG);
      gemm256<0><<<dim3(2, M / 256), 512, 0, stream>>>(
          BIG, WT_F2 + (size_t)l * 512 * 2048, bff2, Y, M, 512, 2048,
          (size_t)l * 512, FLAG);
      add_ln_kernel<<<M, 256, 0, stream>>>(X, Y, ln2g, ln2b, (size_t)l * 512, FLAG);
    }
    pool_kernel<<<nseq, 256, 0, stream>>>(X, mask, pooled, L, moff, FLAG);
  };

  const int seq_per = 480 / NCH;
  for (int c = 0; c < NCH; c++) {
    encode(fact_ids + (size_t)c * seq_per * 64, seq_per, 64, fact_mask,
           (size_t)c * seq_per * 64, FSEQ + (size_t)c * seq_per * 512);
  }
  encode(hyp_ids, 64, 32, hyp_mask, 0, HSEQ);

  pair_score_kernel<<<16 * 30 * 30, 64, 0, stream>>>(FSEQ, FSEQ, absW, absB, AA, 30, 30, FLAG);
  pair_score_kernel<<<16 * 4 * 30, 64, 0, stream>>>(HSEQ, FSEQ, scoreW, scoreB, QA, 4, 30, FLAG);
  aa_softmax_kernel<<<16, 256, 0, stream>>>(AA, AASM);
  qa_softmax_kernel<<<64, 64, 0, stream>>>(QA, SIM);

  edgew_kernel<<<(16 * 1156 + 255) / 256, 256, 0, stream>>>(
      aa_ov, aa_sim_in, qa_ov, qq, AASM, SIM, p_aaov, p_aasim, p_qaov, p_qasim,
      WMAT, FLAG);
  solve_kernel<<<16, 64, 0, stream>>>(WMAT, PRED, out);
  loss_kernel<<<1, 256, 0, stream>>>(SIM, gold, PRED, labels, out, FLAG);
}

// Round 3
// 1346.726 us; speedup vs baseline: 1.1015x; 1.1015x over previous
//
#include <hip/hip_runtime.h>
#include <cstdint>
#include <cstddef>

// ---------------------------------------------------------------------------
// B=16 V=30522 D=512 H=8 DH=64 FF=2048 NC=4 NF=30 NN=34 FL=64 HL=32 L=2
// INPUT float tensors may be fp32 OR bf16 -- detected at runtime from ln1_g
// (all 1.0): fp32 -> first u32 == 0x3F800000 ; bf16 -> 0x3F803F80.
// OUTPUT: 65 FLOAT32 values = [loss, final_pred(16x4)].
// R11 change vs R10 (passed, 1483 us -- REGRESSION vs R9's 1191): R10's
// 8-phase port read fragments in-phase (no LDS||MFMA overlap; LDS-pipe
// 3072 cyc/K-tile/CU > MFMA 2483) and waited vmcnt every phase -> 543 TF,
// the m232 failure mode. R11 = derived-waits port matching m201's
// fingerprints: quadrant order Q00->Q01->Q11->Q10 with ds_reads pipelined
// ONE PHASE AHEAD (per-phase read counts {8,8,4,8}); stages
// {ph0:B0(t+1)->nxt, ph1:A0(t+2)->cur, ph2:B1(t+2)->cur, ph3:A1(t+2)->cur};
// ONE s_waitcnt vmcnt(6) per K-tile at ph3 BEFORE its barrier (confirms
// exactly tile t+2's 4 halves; HBM-critical A0 gets 6-phase slack, L2-hot
// B0 3-phase); ph3's next-tile A0 ds_reads AFTER that barrier (cross-wave
// safety); peeled last tile (no stages/waits); final vmcnt(0) quiesce.
// Every DMA-write-vs-ds_read WAR edge re-verified (stage lands only one
// phase after the region's reads drain at an MFMA lgkm wait + barrier).
// Predicted: FF1 118 -> ~50 us, MfmaUtil 22 -> ~50%+; total ~1000-1080.
// ---------------------------------------------------------------------------

using u16 = unsigned short;

typedef __bf16 bf16x8 __attribute__((ext_vector_type(8)));
typedef float  floatx4 __attribute__((ext_vector_type(4)));

#if defined(__has_builtin)
#if __has_builtin(__builtin_amdgcn_global_load_lds)
#define USE_GLL 1
#endif
#endif

__device__ __forceinline__ float bf2f(u16 u) {
  return __uint_as_float(((unsigned)u) << 16);
}
__device__ __forceinline__ u16 f2bf(float f) {
  unsigned u = __float_as_uint(f);
  u += 0x7FFFu + ((u >> 16) & 1u);   // round-to-nearest-even
  return (u16)(u >> 16);
}
__device__ __forceinline__ float ldf(const void* p, size_t i, int isb) {
  return isb ? bf2f(((const u16*)p)[i]) : ((const float*)p)[i];
}

__device__ __forceinline__ float waveSum(float v) {
#pragma unroll
  for (int o = 32; o > 0; o >>= 1) v += __shfl_xor(v, o, 64);
  return v;
}
__device__ __forceinline__ float waveMax(float v) {
#pragma unroll
  for (int o = 32; o > 0; o >>= 1) v = fmaxf(v, __shfl_xor(v, o, 64));
  return v;
}
__device__ __forceinline__ float blockSum(float v, float* sh4) {
  v = waveSum(v);
  if ((threadIdx.x & 63) == 0) sh4[threadIdx.x >> 6] = v;
  __syncthreads();
  float r = sh4[0] + sh4[1] + sh4[2] + sh4[3];
  __syncthreads();
  return r;
}
__device__ __forceinline__ float blockMax(float v, float* sh4) {
  v = waveMax(v);
  if ((threadIdx.x & 63) == 0) sh4[threadIdx.x >> 6] = v;
  __syncthreads();
  float r = fmaxf(fmaxf(sh4[0], sh4[1]), fmaxf(sh4[2], sh4[3]));
  __syncthreads();
  return r;
}

// ---------------------------------------------------------------------------
__global__ void detect_kernel(const void* __restrict__ ln1g, int* __restrict__ flag) {
  unsigned u = *(const unsigned*)ln1g;
  *flag = (u == 0x3F800000u) ? 0 : 1;
}

// ---------------------------------------------------------------------------
// Transpose + ->bf16: src elements [eoff + k*N + n] -> dst[n*K + k].
// ---------------------------------------------------------------------------
__global__ __launch_bounds__(256) void transpose_kernel(const void* __restrict__ src,
                                                        u16* __restrict__ dst,
                                                        int K, int N, size_t eoff,
                                                        const int* __restrict__ F) {
  const int isb = *F;
  __shared__ u16 tile[32][33];
  int bx = blockIdx.x, by = blockIdx.y;
  int tx = threadIdx.x & 31, ty = threadIdx.x >> 5;
  for (int i = ty; i < 32; i += 8)
    tile[i][tx] = f2bf(ldf(src, eoff + (size_t)(by * 32 + i) * N + bx * 32 + tx, isb));
  __syncthreads();
  for (int i = ty; i < 32; i += 8)
    dst[(size_t)(bx * 32 + i) * K + by * 32 + tx] = tile[tx][i];
}

// ---------------------------------------------------------------------------
// Embedding + positional encoding. One block per token.
// ---------------------------------------------------------------------------
__global__ __launch_bounds__(256) void embed_kernel(const int* __restrict__ ids,
                                                    const void* __restrict__ emb,
                                                    u16* __restrict__ x, int L,
                                                    const int* __restrict__ F) {
  const int isb = *F;
  int tok = blockIdx.x;
  int pos = tok % L;
  int id = ids[tok];
  const float LOG1E4_OVER_D = 9.210340371976184f / 512.0f;
  for (int d = threadIdx.x; d < 512; d += 256) {
    float e = ldf(emb, (size_t)id * 512 + d, isb) * 22.62741699796952f;
    int i2 = d & ~1;
    float ang = (float)pos * expf(-(float)i2 * LOG1E4_OVER_D);
    float pe = (d & 1) ? cosf(ang) : sinf(ang);
    x[(size_t)tok * 512 + d] = f2bf(e + pe);
  }
}

// ---------------------------------------------------------------------------
// 256x256 8-phase GEMM (derived-waits): C = A @ Bt^T + bias (optional relu).
// 512 threads = 8 waves (2M x 4N); per-wave C = 128x64 = acc[8][4] floatx4.
// LDS halves (16 KB each), chunk-rotation swizzle (0 bank conflicts), layout
// identical to R10 (refchecked). Schedule per K-tile (t):
//  ph0: read B1[cur],B0[cur]; stage B0(t+1)->nxt;        bar; MFMA Q00; bar
//  ph1: read A1[cur];         stage A0(t+2)->cur;        bar; MFMA Q01; bar
//  ph2: re-read B0[cur];      stage B1(t+2)->cur;        bar; MFMA Q11; bar
//  ph3: stage A1(t+2)->cur; vmcnt(6); bar; read A0[nxt]; MFMA Q10; bar
// vmcnt(6) at ph3 confirms exactly tile t+2's 4 halves (3 half-tiles stay
// in flight). Last tile peeled (no stages/waits/barriers needed).
// ---------------------------------------------------------------------------
#define GLL16(GP, LP) __builtin_amdgcn_global_load_lds( \
    (const __attribute__((address_space(1))) void*)(GP), \
    (__attribute__((address_space(3))) void*)(LP), 16, 0, 0)

template <int RELU>
__global__ __launch_bounds__(512, 2) void gemm256(const u16* __restrict__ A,
                                                  const u16* __restrict__ Bt,
                                                  const void* __restrict__ bias,
                                                  u16* __restrict__ C,
                                                  int M, int N, int K, size_t boff,
                                                  const int* __restrict__ F) {
  const int isb = *F;
  __shared__ __align__(16) u16 As[2][2][128 * 64];
  __shared__ __align__(16) u16 Bs[2][2][128 * 64];
  const int tid = threadIdx.x;
  const int lane = tid & 63;
  const int wave = tid >> 6;          // 0..7
  const int wm = wave >> 2;           // 0..1 (M)
  const int wnn = wave & 3;           // 0..3 (N)
  const int l15 = lane & 15, quad = lane >> 4;

  // XCD-aware bijective remap (T1, m192/m204), bn fastest per XCD chunk.
  const int nwg = gridDim.x * gridDim.y;
  const int hw = blockIdx.y * gridDim.x + blockIdx.x;
  int lg;
  if ((nwg & 7) == 0) {
    lg = (hw & 7) * (nwg >> 3) + (hw >> 3);
  } else {
    int q = nwg >> 3, r = nwg & 7, xcd = hw & 7, j = hw >> 3;
    lg = (xcd < r ? xcd * (q + 1) : r * (q + 1) + (xcd - r) * q) + j;
  }
  const int bm = lg / gridDim.x;
  const int bn = lg - bm * gridDim.x;

  const u16* Abase = A + (size_t)bm * 256 * K;
  const u16* Bbase = Bt + (size_t)bn * 256 * K;

  // Staging per-thread invariants (layout identical to R10, refchecked).
  const int slr = tid >> 3;                 // local row 0..63 (sweep0)
  const int sp = tid & 7;                   // chunk position 0..7
  const int colrot = ((sp - slr) & 7) * 8;  // rotated source column (elems)
  const int rowB0 = (slr & 31) + ((slr >> 5) << 6);
  const int nt = K >> 6;

#define FENCE asm volatile("" ::: "memory")
#define BARM { FENCE; __builtin_amdgcn_s_barrier(); FENCE; }
#define WAITV(NN_) asm volatile("s_waitcnt vmcnt(" #NN_ ")" ::: "memory")

#define STAGE_A(H, T, BUF) { \
    const u16* g_ = Abase + (size_t)((H) * 64 + slr) * K + (T) * 64 + colrot; \
    u16* d_ = (BUF) + (H) * 8192 + tid * 8; \
    GLL16(g_, d_); \
    GLL16(g_ + (size_t)128 * K, d_ + 4096); }

#define STAGE_B(NH, T, BUF) { \
    const u16* g_ = Bbase + (size_t)((NH) * 32 + rowB0) * K + (T) * 64 + colrot; \
    u16* d_ = (BUF) + (NH) * 8192 + tid * 8; \
    GLL16(g_, d_); \
    GLL16(g_ + (size_t)128 * K, d_ + 4096); }

#define LOADA(DST, H, BUF) { \
    _Pragma("unroll") for (int ks = 0; ks < 2; ks++) \
    _Pragma("unroll") for (int mi = 0; mi < 4; mi++) { \
      int r_ = wm * 64 + mi * 16 + l15; \
      int q_ = ks * 4 + quad; \
      DST[ks][mi] = *(const bf16x8*)((BUF) + (H) * 8192 + r_ * 64 + ((q_ + r_) & 7) * 8); } }

#define LOADB(DST, NH, BUF) { \
    _Pragma("unroll") for (int ks = 0; ks < 2; ks++) \
    _Pragma("unroll") for (int ni = 0; ni < 2; ni++) { \
      int r_ = wnn * 32 + ni * 16 + l15; \
      int q_ = ks * 4 + quad; \
      DST[ks][ni] = *(const bf16x8*)((BUF) + (NH) * 8192 + r_ * 64 + ((q_ + r_) & 7) * 8); } }

#define MFMAQ(FA, FB, MH, NH) { \
    __builtin_amdgcn_s_setprio(1); \
    _Pragma("unroll") for (int ks = 0; ks < 2; ks++) \
    _Pragma("unroll") for (int mi = 0; mi < 4; mi++) \
    _Pragma("unroll") for (int ni = 0; ni < 2; ni++) \
      acc[(MH) * 4 + mi][(NH) * 2 + ni] = __builtin_amdgcn_mfma_f32_16x16x32_bf16( \
          FA[ks][mi], FB[ks][ni], acc[(MH) * 4 + mi][(NH) * 2 + ni], 0, 0, 0); \
    __builtin_amdgcn_s_setprio(0); }

  floatx4 acc[8][4];
#pragma unroll
  for (int i = 0; i < 8; i++)
#pragma unroll
    for (int j = 0; j < 4; j++) acc[i][j] = (floatx4){0.f, 0.f, 0.f, 0.f};

  bf16x8 fa[2][4];    // A0 family (current tile's A-half 0 / next at ph3)
  bf16x8 fa2[2][4];   // A1 family
  bf16x8 fb0[2][2];   // B0 family
  bf16x8 fb1[2][2];   // B1 family

  u16* A0p = &As[0][0][0]; u16* A1p = &As[1][0][0];
  u16* B0p = &Bs[0][0][0]; u16* B1p = &Bs[1][0][0];

  // Prologue: tile0 full (8 loads) + {A0(1), B1(1), A1(1)} (6 loads).
  // vmcnt(6) -> tile0 confirmed for every wave; barrier for cross-wave.
  {
    const int t1 = (nt > 1) ? 1 : 0;
    STAGE_A(0, 0, A0p);
    STAGE_B(0, 0, B0p);
    STAGE_B(1, 0, B0p);
    STAGE_A(1, 0, A0p);
    STAGE_A(0, t1, A1p);
    STAGE_B(1, t1, B1p);
    STAGE_A(1, t1, A1p);
    WAITV(6);
    BARM;
    LOADA(fa, 0, A0p);   // pre-read A0[0] for ph0's Q00
  }

  for (int t = 0; t < nt - 1; ++t) {
    u16* Ac = (t & 1) ? A1p : A0p;
    u16* An = (t & 1) ? A0p : A1p;
    u16* Bc = (t & 1) ? B1p : B0p;
    u16* Bn = (t & 1) ? B0p : B1p;
    const int tp2 = (t + 2 < nt) ? t + 2 : nt - 1;  // clamp: same-data dups
    // ph0 -------------------------------------------------------------
    LOADB(fb1, 1, Bc);
    LOADB(fb0, 0, Bc);
    STAGE_B(0, t + 1, Bn);
    BARM;
    MFMAQ(fa, fb0, 0, 0);
    BARM;
    // ph1 -------------------------------------------------------------
    LOADA(fa2, 1, Ac);
    STAGE_A(0, tp2, Ac);
    BARM;
    MFMAQ(fa, fb1, 0, 1);
    BARM;
    // ph2 -------------------------------------------------------------
    LOADB(fb0, 0, Bc);            // re-read B0 for Q10
    STAGE_B(1, tp2, Bc);
    BARM;
    MFMAQ(fa2, fb1, 1, 1);
    BARM;
    // ph3 -------------------------------------------------------------
    STAGE_A(1, tp2, Ac);
    WAITV(6);                     // confirms tile t+2's 4 halves (all waves)
    BARM;
    LOADA(fa, 0, An);             // next tile's A0 (post-barrier: safe)
    MFMAQ(fa2, fb0, 1, 0);
    BARM;
  }

  // Peeled last tile (nt-1): no stages, no waits, no barriers needed.
  {
    u16* Ac = ((nt - 1) & 1) ? A1p : A0p;
    u16* Bc = ((nt - 1) & 1) ? B1p : B0p;
    LOADB(fb1, 1, Bc);
    LOADB(fb0, 0, Bc);
    MFMAQ(fa, fb0, 0, 0);
    LOADA(fa2, 1, Ac);
    MFMAQ(fa, fb1, 0, 1);
    LOADB(fb0, 0, Bc);
    MFMAQ(fa2, fb1, 1, 1);
    MFMAQ(fa2, fb0, 1, 0);
  }
  WAITV(0);   // quiesce clamped-tail DMAs before endpgm

#pragma unroll
  for (int an = 0; an < 4; an++) {
    int gcol = bn * 256 + wnn * 64 + (an >> 1) * 32 + (an & 1) * 16 + l15;
    float bv = ldf(bias, boff + gcol, isb);
#pragma unroll
    for (int am = 0; am < 8; am++) {
      int growb = bm * 256 + wm * 128 + (am >> 2) * 64 + (am & 3) * 16 + quad * 4;
#pragma unroll
      for (int r = 0; r < 4; r++) {
        float v = acc[am][an][r] + bv;
        if (RELU) v = fmaxf(v, 0.f);
        C[(size_t)(growb + r) * N + gcol] = f2bf(v);
      }
    }
  }
#undef STAGE_A
#undef STAGE_B
#undef LOADA
#undef LOADB
#undef MFMAQ
#undef WAITV
#undef BARM
#undef FENCE
}

// ---------------------------------------------------------------------------
// MFMA attention: one block per (seq, head), 256 threads (2x2 wave grid).
// LDS row stride 72 elems (144 B) -> fragment reads are 2-way (free).
// ---------------------------------------------------------------------------
__global__ __launch_bounds__(256) void attn_kernel(const u16* __restrict__ qkv,
                                                   u16* __restrict__ o, int L) {
  const int h = blockIdx.x & 7;
  const int s = blockIdx.x >> 3;
  __shared__ __align__(16) u16 Qs[64 * 72];   // Q, later reused as P
  __shared__ __align__(16) u16 Ks[64 * 72];
  __shared__ __align__(16) u16 Vt[64 * 72];   // V^T: [d][t]
  __shared__ float Ss[64 * 66];
  const int tid = threadIdx.x;
  const int lane = tid & 63;
  const int wave = tid >> 6;
  const int wm = wave >> 1, wn = wave & 1;
  const int l15 = lane & 15, quad = lane >> 4;
  const int base = s * L;

  for (int idx = tid; idx < 512; idx += 256) {
    int t = idx >> 3, d8 = (idx & 7) * 8;
    if (t < L) {
      size_t g = (size_t)(base + t) * 1536 + h * 64 + d8;
      *(uint4*)&Qs[t * 72 + d8] = *(const uint4*)&qkv[g];
      *(uint4*)&Ks[t * 72 + d8] = *(const uint4*)&qkv[g + 512];
      u16 vv[8];
      *(uint4*)vv = *(const uint4*)&qkv[g + 1024];
#pragma unroll
      for (int i = 0; i < 8; i++) Vt[(d8 + i) * 72 + t] = vv[i];
    } else {
      uint4 z = {0u, 0u, 0u, 0u};
      *(uint4*)&Qs[t * 72 + d8] = z;
      *(uint4*)&Ks[t * 72 + d8] = z;
#pragma unroll
      for (int i = 0; i < 8; i++) Vt[(d8 + i) * 72 + t] = 0;
    }
  }
  __syncthreads();

  {
    floatx4 acc[2][2];
#pragma unroll
    for (int mi = 0; mi < 2; mi++)
#pragma unroll
      for (int ni = 0; ni < 2; ni++) acc[mi][ni] = (floatx4){0.f, 0.f, 0.f, 0.f};
#pragma unroll
    for (int ks = 0; ks < 2; ks++) {
      bf16x8 af[2], bfr[2];
#pragma unroll
      for (int mi = 0; mi < 2; mi++)
        af[mi] = *(const bf16x8*)&Qs[(wm * 32 + mi * 16 + l15) * 72 + ks * 32 + quad * 8];
#pragma unroll
      for (int ni = 0; ni < 2; ni++)
        bfr[ni] = *(const bf16x8*)&Ks[(wn * 32 + ni * 16 + l15) * 72 + ks * 32 + quad * 8];
#pragma unroll
      for (int mi = 0; mi < 2; mi++)
#pragma unroll
        for (int ni = 0; ni < 2; ni++)
          acc[mi][ni] = __builtin_amdgcn_mfma_f32_16x16x32_bf16(af[mi], bfr[ni], acc[mi][ni], 0, 0, 0);
    }
#pragma unroll
    for (int mi = 0; mi < 2; mi++)
#pragma unroll
      for (int ni = 0; ni < 2; ni++)
#pragma unroll
        for (int r = 0; r < 4; r++)
          Ss[(wm * 32 + mi * 16 + quad * 4 + r) * 66 + wn * 32 + ni * 16 + l15] =
              acc[mi][ni][r] * 0.125f;
  }
  __syncthreads();

  {
    int r = tid >> 2, sub = tid & 3;
    int j0 = sub * 16;
    float mx = -3.4e38f;
    if (r < L)
      for (int j = j0; j < j0 + 16; j++)
        if (j < L) mx = fmaxf(mx, Ss[r * 66 + j]);
    mx = fmaxf(mx, __shfl_xor(mx, 1, 64));
    mx = fmaxf(mx, __shfl_xor(mx, 2, 64));
    float sum = 0.f;
    if (r < L)
      for (int j = j0; j < j0 + 16; j++)
        if (j < L) sum += expf(Ss[r * 66 + j] - mx);
    sum += __shfl_xor(sum, 1, 64);
    sum += __shfl_xor(sum, 2, 64);
    float inv = 1.f / sum;
    if (r < L)
      for (int j = j0; j < j0 + 16; j++)
        Qs[r * 72 + j] = (j < L) ? f2bf(expf(Ss[r * 66 + j] - mx) * inv) : (u16)0;
  }
  __syncthreads();

  {
    floatx4 acc[2][2];
#pragma unroll
    for (int mi = 0; mi < 2; mi++)
#pragma unroll
      for (int ni = 0; ni < 2; ni++) acc[mi][ni] = (floatx4){0.f, 0.f, 0.f, 0.f};
#pragma unroll
    for (int ks = 0; ks < 2; ks++) {
      bf16x8 af[2], bfr[2];
#pragma unroll
      for (int mi = 0; mi < 2; mi++)
        af[mi] = *(const bf16x8*)&Qs[(wm * 32 + mi * 16 + l15) * 72 + ks * 32 + quad * 8];
#pragma unroll
      for (int ni = 0; ni < 2; ni++)
        bfr[ni] = *(const bf16x8*)&Vt[(wn * 32 + ni * 16 + l15) * 72 + ks * 32 + quad * 8];
#pragma unroll
      for (int mi = 0; mi < 2; mi++)
#pragma unroll
        for (int ni = 0; ni < 2; ni++)
          acc[mi][ni] = __builtin_amdgcn_mfma_f32_16x16x32_bf16(af[mi], bfr[ni], acc[mi][ni], 0, 0, 0);
    }
#pragma unroll
    for (int mi = 0; mi < 2; mi++) {
#pragma unroll
      for (int r = 0; r < 4; r++) {
        int t = wm * 32 + mi * 16 + quad * 4 + r;
        if (t < L) {
#pragma unroll
          for (int ni = 0; ni < 2; ni++) {
            int d = wn * 32 + ni * 16 + l15;
            o[(size_t)(base + t) * 512 + h * 64 + d] = f2bf(acc[mi][ni][r]);
          }
        }
      }
    }
  }
}

// ---------------------------------------------------------------------------
// x = LayerNorm(x + y) * g[eoff..] + b[eoff..]
// ---------------------------------------------------------------------------
__global__ __launch_bounds__(256) void add_ln_kernel(u16* __restrict__ x,
                                                     const u16* __restrict__ y,
                                                     const void* __restrict__ g,
                                                     const void* __restrict__ b,
                                                     size_t eoff,
                                                     const int* __restrict__ F) {
  const int isb = *F;
  const int row = blockIdx.x, tid = threadIdx.x;
  __shared__ float sh[4];
  size_t o0 = (size_t)row * 512 + tid;
  float v0 = bf2f(x[o0]) + bf2f(y[o0]);
  float v1 = bf2f(x[o0 + 256]) + bf2f(y[o0 + 256]);
  float mean = blockSum(v0 + v1, sh) * (1.f / 512.f);
  float d0 = v0 - mean, d1 = v1 - mean;
  float var = blockSum(d0 * d0 + d1 * d1, sh) * (1.f / 512.f);
  float rstd = rsqrtf(var + 1e-5f);
  x[o0]       = f2bf(d0 * rstd * ldf(g, eoff + tid, isb)       + ldf(b, eoff + tid, isb));
  x[o0 + 256] = f2bf(d1 * rstd * ldf(g, eoff + tid + 256, isb) + ldf(b, eoff + tid + 256, isb));
}

// ---------------------------------------------------------------------------
// Masked mean pool; mask elements at [moff + s*L + t].
// ---------------------------------------------------------------------------
__global__ __launch_bounds__(256) void pool_kernel(const u16* __restrict__ x,
                                                   const void* __restrict__ mask,
                                                   float* __restrict__ pooled, int L,
                                                   size_t moff,
                                                   const int* __restrict__ F) {
  const int isb = *F;
  const int s = blockIdx.x;
  float msum = 0.f;
  for (int t = 0; t < L; t++) msum += ldf(mask, moff + s * L + t, isb);
  float inv = 1.f / fmaxf(msum, 1e-9f);
  for (int d = threadIdx.x; d < 512; d += 256) {
    float acc = 0.f;
    for (int t = 0; t < L; t++)
      acc += bf2f(x[(size_t)(s * L + t) * 512 + d]) * ldf(mask, moff + s * L + t, isb);
    pooled[(size_t)s * 512 + d] = acc * inv;
  }
}

// ---------------------------------------------------------------------------
// Pairwise score
// ---------------------------------------------------------------------------
__global__ __launch_bounds__(64) void pair_score_kernel(const float* __restrict__ X,
                                                        const float* __restrict__ Y,
                                                        const void* __restrict__ Wv,
                                                        const void* __restrict__ bscal,
                                                        float* __restrict__ outp,
                                                        int NI, int NJ,
                                                        const int* __restrict__ F) {
  const int isb = *F;
  int gid = blockIdx.x;
  int j = gid % NJ;
  int t = gid / NJ;
  int i = t % NI;
  int b = t / NI;
  const float* xv = X + ((size_t)b * NI + i) * 512;
  const float* yv = Y + ((size_t)b * NJ + j) * 512;
  int l = threadIdx.x;
  float p = 0.f;
  for (int d = l; d < 512; d += 64) {
    float xi = xv[d], yj = yv[d];
    p += ldf(Wv, d, isb) * yj + ldf(Wv, 512 + d, isb) * xi +
         ldf(Wv, 1024 + d, isb) * fabsf(yj - xi) + ldf(Wv, 1536 + d, isb) * xi * yj;
  }
  p = waveSum(p);
  if (l == 0) outp[gid] = p + ldf(bscal, 0, isb);
}

__global__ __launch_bounds__(256) void aa_softmax_kernel(const float* __restrict__ aa,
                                                         float* __restrict__ aasm) {
  const int b = blockIdx.x;
  const float* src = aa + (size_t)b * 900;
  float* dst = aasm + (size_t)b * 900;
  __shared__ float sh[4];
  int tid = threadIdx.x;
  float mx = -3.4e38f;
  for (int i = tid; i < 900; i += 256) mx = fmaxf(mx, src[i]);
  mx = blockMax(mx, sh);
  float sum = 0.f;
  for (int i = tid; i < 900; i += 256) sum += expf(src[i] - mx);
  sum = blockSum(sum, sh);
  float inv = 1.f / sum;
  for (int i = tid; i < 900; i += 256) {
    int r = i / 30, c = i - r * 30;
    dst[i] = (r == c) ? 0.f : expf(src[i] - mx) * inv;
  }
}

__global__ __launch_bounds__(64) void qa_softmax_kernel(const float* __restrict__ qa,
                                                        float* __restrict__ sim) {
  int g = blockIdx.x;
  int l = threadIdx.x;
  float v = (l < 30) ? qa[(size_t)g * 30 + l] : -3.4e38f;
  float mx = waveMax(v);
  float e = (l < 30) ? expf(v - mx) : 0.f;
  float s = waveSum(e);
  if (l < 30) sim[(size_t)g * 30 + l] = e / s;
}

// ---------------------------------------------------------------------------
// Edge weights
// ---------------------------------------------------------------------------
__global__ __launch_bounds__(256) void edgew_kernel(const void* __restrict__ aaov,
                                                    const void* __restrict__ aasim_in,
                                                    const void* __restrict__ qaov,
                                                    const void* __restrict__ qq,
                                                    const float* __restrict__ aasm,
                                                    const float* __restrict__ sim,
                                                    const void* __restrict__ p1,
                                                    const void* __restrict__ p2,
                                                    const void* __restrict__ p3,
                                                    const void* __restrict__ p4,
                                                    float* __restrict__ Wout,
                                                    const int* __restrict__ F) {
  const int isb = *F;
  int e = blockIdx.x * 256 + threadIdx.x;
  if (e >= 16 * 1156) return;
  int b = e / 1156;
  int rem = e - b * 1156;
  int r = rem / 34, c = rem - r * 34;
  float aas;
  if (r >= 4 && c >= 4) aas = aasm[(size_t)b * 900 + (r - 4) * 30 + (c - 4)];
  else                  aas = ldf(aasim_in, e, isb);
  float qas = 0.f;
  if (r >= 4 && c < 4)      qas = sim[((size_t)b * 4 + c) * 30 + (r - 4)];
  else if (r < 4 && c >= 4) qas = sim[((size_t)b * 4 + r) * 30 + (c - 4)];
  float w = -ldf(p1, 0, isb) * ldf(aaov, e, isb) + ldf(p2, 0, isb) * aas +
            ldf(p3, 0, isb) * ldf(qaov, e, isb) + ldf(p4, 0, isb) * qas +
            ldf(qq, e, isb);
  Wout[e] = w;
}

// ---------------------------------------------------------------------------
// Projected gradient ascent (100 iters), register-resident, barrier-free.
// ---------------------------------------------------------------------------
__global__ __launch_bounds__(64) void solve_kernel(const float* __restrict__ Wmat,
                                                   float* __restrict__ pred,
                                                   float* __restrict__ outp) {
  const int b = blockIdx.x;
  const int lane = threadIdx.x;
  float E[19], Ws[19], As[19];
  bool dg[19];
#pragma unroll
  for (int k = 0; k < 19; k++) {
    int e = lane + (k << 6);
    if (e < 1156) {
      int r = e / 34, c = e - r * 34;
      float w1 = Wmat[(size_t)b * 1156 + e];
      float w2 = Wmat[(size_t)b * 1156 + c * 34 + r];
      Ws[k] = 0.5f * (w1 + w2);
      As[k] = 0.5f * (((w1 != 0.f) ? 1.f : 0.f) + ((w2 != 0.f) ? 1.f : 0.f));
      dg[k] = (r == c && r < 4);
      E[k] = 0.5f;
    } else {
      Ws[k] = 0.f; As[k] = 0.f; dg[k] = false; E[k] = 0.f;
    }
  }
  for (int it = 0; it < 100; it++) {
    float ps = 0.f;
#pragma unroll
    for (int k = 0; k < 19; k++) ps += As[k] * E[k];
    float s = waveSum(ps);
    float dd = __shfl(E[0], 0, 64) + __shfl(E[0], 35, 64) +
               __shfl(E[1], 6, 64) + __shfl(E[1], 41, 64);
    float coef_s = (s > 6.f) ? 20.f * (s - 6.f) : 0.f;
    float coef_d = 20.f * (dd - 1.f);
#pragma unroll
    for (int k = 0; k < 19; k++) {
      float g = Ws[k] - coef_s * As[k] - (dg[k] ? coef_d : 0.f);
      E[k] = fminf(fmaxf(E[k] + 0.05f * g, 0.f), 1.f);
    }
  }
  float v0 = E[0], v1 = E[1];
  if (lane == 0)  { pred[b * 4 + 0] = v0; outp[1 + b * 4 + 0] = v0; }
  if (lane == 35) { pred[b * 4 + 1] = v0; outp[1 + b * 4 + 1] = v0; }
  if (lane == 6)  { pred[b * 4 + 2] = v1; outp[1 + b * 4 + 2] = v1; }
  if (lane == 41) { pred[b * 4 + 3] = v1; outp[1 + b * 4 + 3] = v1; }
}

// ---------------------------------------------------------------------------
// Final loss: out[0] = ce(log_softmax(pred), labels) + mse(sim, gold_sm)
// ---------------------------------------------------------------------------
__global__ __launch_bounds__(256) void loss_kernel(const float* __restrict__ sim,
                                                   const void* __restrict__ gold,
                                                   const float* __restrict__ pred,
                                                   const int* __restrict__ labels,
                                                   float* __restrict__ outp,
                                                   const int* __restrict__ F) {
  const int isb = *F;
  __shared__ float sh[4];
  const int tid = threadIdx.x;
  float local = 0.f;
  if (tid < 64) {
    float mx = -3.4e38f;
    for (int k = 0; k < 30; k++) mx = fmaxf(mx, ldf(gold, (size_t)tid * 30 + k, isb));
    float sum = 0.f;
    for (int k = 0; k < 30; k++) sum += expf(ldf(gold, (size_t)tid * 30 + k, isb) - mx);
    float inv = 1.f / sum;
    for (int k = 0; k < 30; k++) {
      float gsm = expf(ldf(gold, (size_t)tid * 30 + k, isb) - mx) * inv;
      float d = sim[(size_t)tid * 30 + k] - gsm;
      local += d * d;
    }
  }
  float mse = blockSum(local, sh) * (1.f / 1920.f);
  float cel = 0.f;
  if (tid < 16) {
    const float* f = pred + tid * 4;
    int lb = labels[tid] & 3;
    float mx = fmaxf(fmaxf(f[0], f[1]), fmaxf(f[2], f[3]));
    float lse = logf(expf(f[0] - mx) + expf(f[1] - mx) + expf(f[2] - mx) + expf(f[3] - mx));
    float lp = f[lb] - mx - lse;
    cel = -lp * (1.f / 16.f);
  }
  float ce = blockSum(cel, sh);
  if (tid == 0) outp[0] = ce + mse;
}

// ---------------------------------------------------------------------------
// Host orchestration
// ---------------------------------------------------------------------------
extern "C" void kernel_launch(void* const* d_in, const int* in_sizes, int n_in,
                              void* d_out, int out_size, void* d_ws, size_t ws_size,
                              hipStream_t stream) {
  (void)in_sizes; (void)n_in; (void)out_size;
  const int*  hyp_ids   = (const int*)d_in[0];
  const void* hyp_mask  = d_in[1];
  const void* fact_mask = d_in[2];
  const int*  fact_ids  = (const int*)d_in[3];
  const void* aa_ov     = d_in[5];
  const void* aa_sim_in = d_in[6];
  const void* qa_ov     = d_in[8];
  const void* qq        = d_in[11];
  const int*  labels    = (const int*)d_in[12];
  const void* gold      = d_in[13];
  const void* emb       = d_in[14];
  const void* Wqkv      = d_in[15];
  const void* bqkv      = d_in[16];
  const void* Wo        = d_in[17];
  const void* bo        = d_in[18];
  const void* ln1g      = d_in[19];
  const void* ln1b      = d_in[20];
  const void* Wff1      = d_in[21];
  const void* bff1      = d_in[22];
  const void* Wff2      = d_in[23];
  const void* bff2      = d_in[24];
  const void* ln2g      = d_in[25];
  const void* ln2b      = d_in[26];
  const void* scoreW    = d_in[27];
  const void* scoreB    = d_in[28];
  const void* absW      = d_in[29];
  const void* absB      = d_in[30];
  const void* p_aaov    = d_in[31];
  const void* p_aasim   = d_in[32];
  const void* p_qaov    = d_in[33];
  const void* p_qasim   = d_in[34];
  float* out = (float*)d_out;

  char* ws = (char*)d_ws;
  size_t off = 0;
  auto alloc = [&](size_t bytes) -> void* {
    void* p = ws + off;
    off += (bytes + 255) & ~(size_t)255;
    return p;
  };

  float* PRED = (float*)alloc(64ull * 4);
  int*   FLAG = (int*)alloc(256);
  float* SIM  = (float*)alloc(16ull * 120 * 4);
  float* QA   = (float*)alloc(16ull * 120 * 4);
  float* AASM = (float*)alloc(16ull * 900 * 4);
  float* AA   = (float*)alloc(16ull * 900 * 4);
  float* WMAT = (float*)alloc(16ull * 1156 * 4);
  float* FSEQ = (float*)alloc(480ull * 512 * 4);
  float* HSEQ = (float*)alloc(64ull * 512 * 4);
  u16* WT_QKV = (u16*)alloc(2ull * 1536 * 512 * 2);
  u16* WT_O   = (u16*)alloc(2ull * 512 * 512 * 2);
  u16* WT_F1  = (u16*)alloc(2ull * 2048 * 512 * 2);
  u16* WT_F2  = (u16*)alloc(2ull * 512 * 2048 * 2);

  // Dynamic chunking from ws_size (constant per process -> graph-safe).
  // All chunk sizes are multiples of 256 tokens (gemm256 tile constraint).
  const int opts_tok[5] = {30720, 15360, 10240, 6144, 3072};
  const int opts_nch[5] = {1, 2, 3, 5, 10};
  int CH_TOK = 3072, NCH = 10;
  for (int i = 0; i < 5; i++) {
    size_t need = off + (size_t)opts_tok[i] * 7168 + 4096;
    if (need <= ws_size) { CH_TOK = opts_tok[i]; NCH = opts_nch[i]; break; }
  }
  u16* X   = (u16*)alloc((size_t)CH_TOK * 512 * 2);
  u16* BIG = (u16*)alloc((size_t)CH_TOK * 2048 * 2);
  u16* ATT = (u16*)alloc((size_t)CH_TOK * 512 * 2);
  u16* Y   = (u16*)alloc((size_t)CH_TOK * 512 * 2);

  detect_kernel<<<1, 1, 0, stream>>>(ln1g, FLAG);

  for (int l = 0; l < 2; l++) {
    transpose_kernel<<<dim3(48, 16), 256, 0, stream>>>(
        Wqkv, WT_QKV + (size_t)l * 1536 * 512, 512, 1536, (size_t)l * 512 * 1536, FLAG);
    transpose_kernel<<<dim3(16, 16), 256, 0, stream>>>(
        Wo, WT_O + (size_t)l * 512 * 512, 512, 512, (size_t)l * 512 * 512, FLAG);
    transpose_kernel<<<dim3(64, 16), 256, 0, stream>>>(
        Wff1, WT_F1 + (size_t)l * 2048 * 512, 512, 2048, (size_t)l * 512 * 2048, FLAG);
    transpose_kernel<<<dim3(16, 64), 256, 0, stream>>>(
        Wff2, WT_F2 + (size_t)l * 512 * 2048, 2048, 512, (size_t)l * 2048 * 512, FLAG);
  }

  auto encode = [&](const int* ids, int nseq, int L, const void* mask,
                    size_t moff, float* pooled) {
    int M = nseq * L;   // multiple of 256
    embed_kernel<<<M, 256, 0, stream>>>(ids, emb, X, L, FLAG);
    for (int l = 0; l < 2; l++) {
      gemm256<0><<<dim3(6, M / 256), 512, 0, stream>>>(
          X, WT_QKV + (size_t)l * 1536 * 512, bqkv, BIG, M, 1536, 512,
          (size_t)l * 1536, FLAG);
      attn_kernel<<<nseq * 8, 256, 0, stream>>>(BIG, ATT, L);
      gemm256<0><<<dim3(2, M / 256), 512, 0, stream>>>(
          ATT, WT_O + (size_t)l * 512 * 512, bo, Y, M, 512, 512,
          (size_t)l * 512, FLAG);
      add_ln_kernel<<<M, 256, 0, stream>>>(X, Y, ln1g, ln1b, (size_t)l * 512, FLAG);
      gemm256<1><<<dim3(8, M / 256), 512, 0, stream>>>(
          X, WT_F1 + (size_t)l * 2048 * 512, bff1, BIG, M, 2048, 512,
          (size_t)l * 2048, FLAG);
      gemm256<0><<<dim3(2, M / 256), 512, 0, stream>>>(
          BIG, WT_F2 + (size_t)l * 512 * 2048, bff2, Y, M, 512, 2048,
          (size_t)l * 512, FLAG);
      add_ln_kernel<<<M, 256, 0, stream>>>(X, Y, ln2g, ln2b, (size_t)l * 512, FLAG);
    }
    pool_kernel<<<nseq, 256, 0, stream>>>(X, mask, pooled, L, moff, FLAG);
  };

  const int seq_per = 480 / NCH;
  for (int c = 0; c < NCH; c++) {
    encode(fact_ids + (size_t)c * seq_per * 64, seq_per, 64, fact_mask,
           (size_t)c * seq_per * 64, FSEQ + (size_t)c * seq_per * 512);
  }
  encode(hyp_ids, 64, 32, hyp_mask, 0, HSEQ);

  pair_score_kernel<<<16 * 30 * 30, 64, 0, stream>>>(FSEQ, FSEQ, absW, absB, AA, 30, 30, FLAG);
  pair_score_kernel<<<16 * 4 * 30, 64, 0, stream>>>(HSEQ, FSEQ, scoreW, scoreB, QA, 4, 30, FLAG);
  aa_softmax_kernel<<<16, 256, 0, stream>>>(AA, AASM);
  qa_softmax_kernel<<<64, 64, 0, stream>>>(QA, SIM);

  edgew_kernel<<<(16 * 1156 + 255) / 256, 256, 0, stream>>>(
      aa_ov, aa_sim_in, qa_ov, qq, AASM, SIM, p_aaov, p_aasim, p_qaov, p_qasim,
      WMAT, FLAG);
  solve_kernel<<<16, 64, 0, stream>>>(WMAT, PRED, out);
  loss_kernel<<<1, 256, 0, stream>>>(SIM, gold, PRED, labels, out, FLAG);
}

// Round 4
// 1022.831 us; speedup vs baseline: 1.4503x; 1.3167x over previous
//
#include <hip/hip_runtime.h>
#include <cstdint>
#include <cstddef>

// ---------------------------------------------------------------------------
// B=16 V=30522 D=512 H=8 DH=64 FF=2048 NC=4 NF=30 NN=34 FL=64 HL=32 L=2
// INPUT float tensors may be fp32 OR bf16 -- detected at runtime from ln1_g
// (all 1.0): fp32 -> first u32 == 0x3F800000 ; bf16 -> 0x3F803F80.
// OUTPUT: 65 FLOAT32 values = [loss, final_pred(16x4)].
// R12 change vs R11 (passed, 1346 us): REVERT GEMM to R9's gemm_bt (78.7 us
// FF1 vs gemm256's 104; two 8-phase attempts both missed prediction -> drop
// that line). Keep R8 LDS chunk-rotation (0 conflicts) + R9 XCD swizzle.
// New in R12:
//  (1) gemm_bt epilogue write reorder: ni innermost so each 128B C row
//      segment is written in 4 back-to-back stores (R9 FF1 WRITE=170MB vs
//      ideal 126MB = partial-line evictions; predict ~140-150MB).
//  (2) Combined fact+hyp encoder pass (M=30720+2048=32768) when ws allows:
//      one layer loop instead of two; attn/pool launched per-stream at the
//      right offsets. Removes ~12 launches + under-occupied M=2048 GEMMs.
//      Fallback to chunked path when ws is small (ws_size is process-
//      constant -> graph-safe branching).
//  (3) add_ln vectorized (packed 2x bf16 loads/stores, G13).
// Predicted: total ~1060-1110 us.
// ---------------------------------------------------------------------------

using u16 = unsigned short;

typedef __bf16 bf16x8 __attribute__((ext_vector_type(8)));
typedef float  floatx4 __attribute__((ext_vector_type(4)));

#if defined(__has_builtin)
#if __has_builtin(__builtin_amdgcn_global_load_lds)
#define USE_GLL 1
#endif
#endif

__device__ __forceinline__ float bf2f(u16 u) {
  return __uint_as_float(((unsigned)u) << 16);
}
__device__ __forceinline__ u16 f2bf(float f) {
  unsigned u = __float_as_uint(f);
  u += 0x7FFFu + ((u >> 16) & 1u);   // round-to-nearest-even
  return (u16)(u >> 16);
}
__device__ __forceinline__ float ldf(const void* p, size_t i, int isb) {
  return isb ? bf2f(((const u16*)p)[i]) : ((const float*)p)[i];
}

__device__ __forceinline__ float waveSum(float v) {
#pragma unroll
  for (int o = 32; o > 0; o >>= 1) v += __shfl_xor(v, o, 64);
  return v;
}
__device__ __forceinline__ float waveMax(float v) {
#pragma unroll
  for (int o = 32; o > 0; o >>= 1) v = fmaxf(v, __shfl_xor(v, o, 64));
  return v;
}
__device__ __forceinline__ float blockSum(float v, float* sh4) {
  v = waveSum(v);
  if ((threadIdx.x & 63) == 0) sh4[threadIdx.x >> 6] = v;
  __syncthreads();
  float r = sh4[0] + sh4[1] + sh4[2] + sh4[3];
  __syncthreads();
  return r;
}
__device__ __forceinline__ float blockMax(float v, float* sh4) {
  v = waveMax(v);
  if ((threadIdx.x & 63) == 0) sh4[threadIdx.x >> 6] = v;
  __syncthreads();
  float r = fmaxf(fmaxf(sh4[0], sh4[1]), fmaxf(sh4[2], sh4[3]));
  __syncthreads();
  return r;
}

// ---------------------------------------------------------------------------
__global__ void detect_kernel(const void* __restrict__ ln1g, int* __restrict__ flag) {
  unsigned u = *(const unsigned*)ln1g;
  *flag = (u == 0x3F800000u) ? 0 : 1;
}

// ---------------------------------------------------------------------------
// Transpose + ->bf16: src elements [eoff + k*N + n] -> dst[n*K + k].
// ---------------------------------------------------------------------------
__global__ __launch_bounds__(256) void transpose_kernel(const void* __restrict__ src,
                                                        u16* __restrict__ dst,
                                                        int K, int N, size_t eoff,
                                                        const int* __restrict__ F) {
  const int isb = *F;
  __shared__ u16 tile[32][33];
  int bx = blockIdx.x, by = blockIdx.y;
  int tx = threadIdx.x & 31, ty = threadIdx.x >> 5;
  for (int i = ty; i < 32; i += 8)
    tile[i][tx] = f2bf(ldf(src, eoff + (size_t)(by * 32 + i) * N + bx * 32 + tx, isb));
  __syncthreads();
  for (int i = ty; i < 32; i += 8)
    dst[(size_t)(bx * 32 + i) * K + by * 32 + tx] = tile[tx][i];
}

// ---------------------------------------------------------------------------
// Embedding + positional encoding. One block per token.
// ---------------------------------------------------------------------------
__global__ __launch_bounds__(256) void embed_kernel(const int* __restrict__ ids,
                                                    const void* __restrict__ emb,
                                                    u16* __restrict__ x, int L,
                                                    const int* __restrict__ F) {
  const int isb = *F;
  int tok = blockIdx.x;
  int pos = tok % L;
  int id = ids[tok];
  const float LOG1E4_OVER_D = 9.210340371976184f / 512.0f;
  for (int d = threadIdx.x; d < 512; d += 256) {
    float e = ldf(emb, (size_t)id * 512 + d, isb) * 22.62741699796952f;
    int i2 = d & ~1;
    float ang = (float)pos * expf(-(float)i2 * LOG1E4_OVER_D);
    float pe = (d & 1) ? cosf(ang) : sinf(ang);
    x[(size_t)tok * 512 + d] = f2bf(e + pe);
  }
}

// ---------------------------------------------------------------------------
// GEMM: C[M][N] = A[M][K] @ Bt[N][K]^T + bias[boff..]  (optional relu)
// bf16 in, fp32 MFMA accumulate, bf16 out. 128x128 tile, BK=64, 256 threads.
// LDS layout: row r holds its eight 16B chunks ROTATED: global chunk q at
// position (q + r) & 7 (0 bank conflicts). XCD-chunked bijective swizzle of
// (bm,bn): A-panel sharers co-reside on one XCD L2.
// R12: epilogue writes row-major (ni innermost) so each 128B line is
// assembled by 4 back-to-back stores (reduces partial-line evictions).
// ---------------------------------------------------------------------------
template <int RELU>
__global__ __launch_bounds__(256, 2) void gemm_bt(const u16* __restrict__ A,
                                                  const u16* __restrict__ Bt,
                                                  const void* __restrict__ bias,
                                                  u16* __restrict__ C,
                                                  int M, int N, int K, size_t boff,
                                                  const int* __restrict__ F) {
  const int isb = *F;
  __shared__ __align__(16) u16 As[128 * 64];
  __shared__ __align__(16) u16 Bs[128 * 64];
  const int tid = threadIdx.x;
  const int lane = tid & 63;
  const int wave = tid >> 6;
  const int wm = wave >> 1, wn = wave & 1;
  const int l15 = lane & 15, quad = lane >> 4;

  // --- XCD-aware bijective remap (T1, m192/m204) ---
  const int nwg = gridDim.x * gridDim.y;
  const int hw  = blockIdx.y * gridDim.x + blockIdx.x;
  int lg;
  if ((nwg & 7) == 0) {
    lg = (hw & 7) * (nwg >> 3) + (hw >> 3);
  } else {
    int q = nwg >> 3, r = nwg & 7;
    int xcd = hw & 7, j = hw >> 3;
    lg = (xcd < r ? xcd * (q + 1) : r * (q + 1) + (xcd - r) * q) + j;
  }
  const int bm = lg / gridDim.x;
  const int bn = lg - bm * gridDim.x;

  floatx4 acc[4][4];
#pragma unroll
  for (int i = 0; i < 4; i++)
#pragma unroll
    for (int j = 0; j < 4; j++) acc[i][j] = (floatx4){0.f, 0.f, 0.f, 0.f};

  const u16* Abase = A + (size_t)bm * 128 * K;
  const u16* Bbase = Bt + (size_t)bn * 128 * K;

  for (int kt = 0; kt < K; kt += 64) {
#pragma unroll
    for (int i = 0; i < 4; i++) {
      int c = i * 256 + tid;             // LDS chunk id 0..1023 (lane-contig)
      int row = c >> 3, p = c & 7;
      int col = (((p - row) & 7)) * 8;   // rotated source chunk (same 128B line)
      const u16* ga = &Abase[(size_t)row * K + kt + col];
      const u16* gb = &Bbase[(size_t)row * K + kt + col];
#ifdef USE_GLL
      __builtin_amdgcn_global_load_lds(
          (const __attribute__((address_space(1))) void*)ga,
          (__attribute__((address_space(3))) void*)&As[c * 8], 16, 0, 0);
      __builtin_amdgcn_global_load_lds(
          (const __attribute__((address_space(1))) void*)gb,
          (__attribute__((address_space(3))) void*)&Bs[c * 8], 16, 0, 0);
#else
      *(uint4*)&As[c * 8] = *(const uint4*)ga;
      *(uint4*)&Bs[c * 8] = *(const uint4*)gb;
#endif
    }
    __syncthreads();
#pragma unroll
    for (int ks = 0; ks < 2; ks++) {
      bf16x8 af[4], bfr[4];
#pragma unroll
      for (int mi = 0; mi < 4; mi++) {
        int ra = wm * 64 + mi * 16 + l15;
        int q = ks * 4 + quad;
        af[mi] = *(const bf16x8*)&As[ra * 64 + ((q + ra) & 7) * 8];
      }
#pragma unroll
      for (int ni = 0; ni < 4; ni++) {
        int rb = wn * 64 + ni * 16 + l15;
        int q = ks * 4 + quad;
        bfr[ni] = *(const bf16x8*)&Bs[rb * 64 + ((q + rb) & 7) * 8];
      }
#pragma unroll
      for (int mi = 0; mi < 4; mi++)
#pragma unroll
        for (int ni = 0; ni < 4; ni++)
          acc[mi][ni] = __builtin_amdgcn_mfma_f32_16x16x32_bf16(af[mi], bfr[ni], acc[mi][ni], 0, 0, 0);
    }
    __syncthreads();
  }

  // Epilogue: ni innermost -> each 128B row segment written back-to-back.
  float bv[4];
  const int gcb = bn * 128 + wn * 64 + l15;
#pragma unroll
  for (int ni = 0; ni < 4; ni++) bv[ni] = ldf(bias, boff + gcb + ni * 16, isb);
#pragma unroll
  for (int mi = 0; mi < 4; mi++) {
#pragma unroll
    for (int r = 0; r < 4; r++) {
      int grow = bm * 128 + wm * 64 + mi * 16 + quad * 4 + r;
      size_t rb = (size_t)grow * N + gcb;
#pragma unroll
      for (int ni = 0; ni < 4; ni++) {
        float v = acc[mi][ni][r] + bv[ni];
        if (RELU) v = fmaxf(v, 0.f);
        C[rb + ni * 16] = f2bf(v);
      }
    }
  }
}

// ---------------------------------------------------------------------------
// MFMA attention: one block per (seq, head), 256 threads (2x2 wave grid).
// LDS row stride 72 elems (144 B) -> fragment reads are 2-way (free).
// ---------------------------------------------------------------------------
__global__ __launch_bounds__(256) void attn_kernel(const u16* __restrict__ qkv,
                                                   u16* __restrict__ o, int L) {
  const int h = blockIdx.x & 7;
  const int s = blockIdx.x >> 3;
  __shared__ __align__(16) u16 Qs[64 * 72];   // Q, later reused as P
  __shared__ __align__(16) u16 Ks[64 * 72];
  __shared__ __align__(16) u16 Vt[64 * 72];   // V^T: [d][t]
  __shared__ float Ss[64 * 66];
  const int tid = threadIdx.x;
  const int lane = tid & 63;
  const int wave = tid >> 6;
  const int wm = wave >> 1, wn = wave & 1;
  const int l15 = lane & 15, quad = lane >> 4;
  const int base = s * L;

  for (int idx = tid; idx < 512; idx += 256) {
    int t = idx >> 3, d8 = (idx & 7) * 8;
    if (t < L) {
      size_t g = (size_t)(base + t) * 1536 + h * 64 + d8;
      *(uint4*)&Qs[t * 72 + d8] = *(const uint4*)&qkv[g];
      *(uint4*)&Ks[t * 72 + d8] = *(const uint4*)&qkv[g + 512];
      u16 vv[8];
      *(uint4*)vv = *(const uint4*)&qkv[g + 1024];
#pragma unroll
      for (int i = 0; i < 8; i++) Vt[(d8 + i) * 72 + t] = vv[i];
    } else {
      uint4 z = {0u, 0u, 0u, 0u};
      *(uint4*)&Qs[t * 72 + d8] = z;
      *(uint4*)&Ks[t * 72 + d8] = z;
#pragma unroll
      for (int i = 0; i < 8; i++) Vt[(d8 + i) * 72 + t] = 0;
    }
  }
  __syncthreads();

  {
    floatx4 acc[2][2];
#pragma unroll
    for (int mi = 0; mi < 2; mi++)
#pragma unroll
      for (int ni = 0; ni < 2; ni++) acc[mi][ni] = (floatx4){0.f, 0.f, 0.f, 0.f};
#pragma unroll
    for (int ks = 0; ks < 2; ks++) {
      bf16x8 af[2], bfr[2];
#pragma unroll
      for (int mi = 0; mi < 2; mi++)
        af[mi] = *(const bf16x8*)&Qs[(wm * 32 + mi * 16 + l15) * 72 + ks * 32 + quad * 8];
#pragma unroll
      for (int ni = 0; ni < 2; ni++)
        bfr[ni] = *(const bf16x8*)&Ks[(wn * 32 + ni * 16 + l15) * 72 + ks * 32 + quad * 8];
#pragma unroll
      for (int mi = 0; mi < 2; mi++)
#pragma unroll
        for (int ni = 0; ni < 2; ni++)
          acc[mi][ni] = __builtin_amdgcn_mfma_f32_16x16x32_bf16(af[mi], bfr[ni], acc[mi][ni], 0, 0, 0);
    }
#pragma unroll
    for (int mi = 0; mi < 2; mi++)
#pragma unroll
      for (int ni = 0; ni < 2; ni++)
#pragma unroll
        for (int r = 0; r < 4; r++)
          Ss[(wm * 32 + mi * 16 + quad * 4 + r) * 66 + wn * 32 + ni * 16 + l15] =
              acc[mi][ni][r] * 0.125f;
  }
  __syncthreads();

  {
    int r = tid >> 2, sub = tid & 3;
    int j0 = sub * 16;
    float mx = -3.4e38f;
    if (r < L)
      for (int j = j0; j < j0 + 16; j++)
        if (j < L) mx = fmaxf(mx, Ss[r * 66 + j]);
    mx = fmaxf(mx, __shfl_xor(mx, 1, 64));
    mx = fmaxf(mx, __shfl_xor(mx, 2, 64));
    float sum = 0.f;
    if (r < L)
      for (int j = j0; j < j0 + 16; j++)
        if (j < L) sum += expf(Ss[r * 66 + j] - mx);
    sum += __shfl_xor(sum, 1, 64);
    sum += __shfl_xor(sum, 2, 64);
    float inv = 1.f / sum;
    if (r < L)
      for (int j = j0; j < j0 + 16; j++)
        Qs[r * 72 + j] = (j < L) ? f2bf(expf(Ss[r * 66 + j] - mx) * inv) : (u16)0;
  }
  __syncthreads();

  {
    floatx4 acc[2][2];
#pragma unroll
    for (int mi = 0; mi < 2; mi++)
#pragma unroll
      for (int ni = 0; ni < 2; ni++) acc[mi][ni] = (floatx4){0.f, 0.f, 0.f, 0.f};
#pragma unroll
    for (int ks = 0; ks < 2; ks++) {
      bf16x8 af[2], bfr[2];
#pragma unroll
      for (int mi = 0; mi < 2; mi++)
        af[mi] = *(const bf16x8*)&Qs[(wm * 32 + mi * 16 + l15) * 72 + ks * 32 + quad * 8];
#pragma unroll
      for (int ni = 0; ni < 2; ni++)
        bfr[ni] = *(const bf16x8*)&Vt[(wn * 32 + ni * 16 + l15) * 72 + ks * 32 + quad * 8];
#pragma unroll
      for (int mi = 0; mi < 2; mi++)
#pragma unroll
        for (int ni = 0; ni < 2; ni++)
          acc[mi][ni] = __builtin_amdgcn_mfma_f32_16x16x32_bf16(af[mi], bfr[ni], acc[mi][ni], 0, 0, 0);
    }
#pragma unroll
    for (int mi = 0; mi < 2; mi++) {
#pragma unroll
      for (int r = 0; r < 4; r++) {
        int t = wm * 32 + mi * 16 + quad * 4 + r;
        if (t < L) {
#pragma unroll
          for (int ni = 0; ni < 2; ni++) {
            int d = wn * 32 + ni * 16 + l15;
            o[(size_t)(base + t) * 512 + h * 64 + d] = f2bf(acc[mi][ni][r]);
          }
        }
      }
    }
  }
}

// ---------------------------------------------------------------------------
// x = LayerNorm(x + y) * g[eoff..] + b[eoff..]   (packed 2x bf16 per thread)
// ---------------------------------------------------------------------------
__global__ __launch_bounds__(256) void add_ln_kernel(u16* __restrict__ x,
                                                     const u16* __restrict__ y,
                                                     const void* __restrict__ g,
                                                     const void* __restrict__ b,
                                                     size_t eoff,
                                                     const int* __restrict__ F) {
  const int isb = *F;
  const int row = blockIdx.x, tid = threadIdx.x;
  __shared__ float sh[4];
  size_t o0 = (size_t)row * 512 + tid * 2;
  unsigned xv = *(const unsigned*)&x[o0];
  unsigned yv = *(const unsigned*)&y[o0];
  float v0 = bf2f((u16)xv) + bf2f((u16)yv);
  float v1 = bf2f((u16)(xv >> 16)) + bf2f((u16)(yv >> 16));
  float mean = blockSum(v0 + v1, sh) * (1.f / 512.f);
  float d0 = v0 - mean, d1 = v1 - mean;
  float var = blockSum(d0 * d0 + d1 * d1, sh) * (1.f / 512.f);
  float rstd = rsqrtf(var + 1e-5f);
  float g0 = ldf(g, eoff + tid * 2, isb),     g1 = ldf(g, eoff + tid * 2 + 1, isb);
  float b0 = ldf(b, eoff + tid * 2, isb),     b1 = ldf(b, eoff + tid * 2 + 1, isb);
  unsigned r0 = f2bf(d0 * rstd * g0 + b0);
  unsigned r1 = f2bf(d1 * rstd * g1 + b1);
  *(unsigned*)&x[o0] = r0 | (r1 << 16);
}

// ---------------------------------------------------------------------------
// Masked mean pool; mask elements at [moff + s*L + t].
// ---------------------------------------------------------------------------
__global__ __launch_bounds__(256) void pool_kernel(const u16* __restrict__ x,
                                                   const void* __restrict__ mask,
                                                   float* __restrict__ pooled, int L,
                                                   size_t moff,
                                                   const int* __restrict__ F) {
  const int isb = *F;
  const int s = blockIdx.x;
  float msum = 0.f;
  for (int t = 0; t < L; t++) msum += ldf(mask, moff + s * L + t, isb);
  float inv = 1.f / fmaxf(msum, 1e-9f);
  for (int d = threadIdx.x; d < 512; d += 256) {
    float acc = 0.f;
    for (int t = 0; t < L; t++)
      acc += bf2f(x[(size_t)(s * L + t) * 512 + d]) * ldf(mask, moff + s * L + t, isb);
    pooled[(size_t)s * 512 + d] = acc * inv;
  }
}

// ---------------------------------------------------------------------------
// Pairwise score
// ---------------------------------------------------------------------------
__global__ __launch_bounds__(64) void pair_score_kernel(const float* __restrict__ X,
                                                        const float* __restrict__ Y,
                                                        const void* __restrict__ Wv,
                                                        const void* __restrict__ bscal,
                                                        float* __restrict__ outp,
                                                        int NI, int NJ,
                                                        const int* __restrict__ F) {
  const int isb = *F;
  int gid = blockIdx.x;
  int j = gid % NJ;
  int t = gid / NJ;
  int i = t % NI;
  int b = t / NI;
  const float* xv = X + ((size_t)b * NI + i) * 512;
  const float* yv = Y + ((size_t)b * NJ + j) * 512;
  int l = threadIdx.x;
  float p = 0.f;
  for (int d = l; d < 512; d += 64) {
    float xi = xv[d], yj = yv[d];
    p += ldf(Wv, d, isb) * yj + ldf(Wv, 512 + d, isb) * xi +
         ldf(Wv, 1024 + d, isb) * fabsf(yj - xi) + ldf(Wv, 1536 + d, isb) * xi * yj;
  }
  p = waveSum(p);
  if (l == 0) outp[gid] = p + ldf(bscal, 0, isb);
}

__global__ __launch_bounds__(256) void aa_softmax_kernel(const float* __restrict__ aa,
                                                         float* __restrict__ aasm) {
  const int b = blockIdx.x;
  const float* src = aa + (size_t)b * 900;
  float* dst = aasm + (size_t)b * 900;
  __shared__ float sh[4];
  int tid = threadIdx.x;
  float mx = -3.4e38f;
  for (int i = tid; i < 900; i += 256) mx = fmaxf(mx, src[i]);
  mx = blockMax(mx, sh);
  float sum = 0.f;
  for (int i = tid; i < 900; i += 256) sum += expf(src[i] - mx);
  sum = blockSum(sum, sh);
  float inv = 1.f / sum;
  for (int i = tid; i < 900; i += 256) {
    int r = i / 30, c = i - r * 30;
    dst[i] = (r == c) ? 0.f : expf(src[i] - mx) * inv;
  }
}

__global__ __launch_bounds__(64) void qa_softmax_kernel(const float* __restrict__ qa,
                                                        float* __restrict__ sim) {
  int g = blockIdx.x;
  int l = threadIdx.x;
  float v = (l < 30) ? qa[(size_t)g * 30 + l] : -3.4e38f;
  float mx = waveMax(v);
  float e = (l < 30) ? expf(v - mx) : 0.f;
  float s = waveSum(e);
  if (l < 30) sim[(size_t)g * 30 + l] = e / s;
}

// ---------------------------------------------------------------------------
// Edge weights
// ---------------------------------------------------------------------------
__global__ __launch_bounds__(256) void edgew_kernel(const void* __restrict__ aaov,
                                                    const void* __restrict__ aasim_in,
                                                    const void* __restrict__ qaov,
                                                    const void* __restrict__ qq,
                                                    const float* __restrict__ aasm,
                                                    const float* __restrict__ sim,
                                                    const void* __restrict__ p1,
                                                    const void* __restrict__ p2,
                                                    const void* __restrict__ p3,
                                                    const void* __restrict__ p4,
                                                    float* __restrict__ Wout,
                                                    const int* __restrict__ F) {
  const int isb = *F;
  int e = blockIdx.x * 256 + threadIdx.x;
  if (e >= 16 * 1156) return;
  int b = e / 1156;
  int rem = e - b * 1156;
  int r = rem / 34, c = rem - r * 34;
  float aas;
  if (r >= 4 && c >= 4) aas = aasm[(size_t)b * 900 + (r - 4) * 30 + (c - 4)];
  else                  aas = ldf(aasim_in, e, isb);
  float qas = 0.f;
  if (r >= 4 && c < 4)      qas = sim[((size_t)b * 4 + c) * 30 + (r - 4)];
  else if (r < 4 && c >= 4) qas = sim[((size_t)b * 4 + r) * 30 + (c - 4)];
  float w = -ldf(p1, 0, isb) * ldf(aaov, e, isb) + ldf(p2, 0, isb) * aas +
            ldf(p3, 0, isb) * ldf(qaov, e, isb) + ldf(p4, 0, isb) * qas +
            ldf(qq, e, isb);
  Wout[e] = w;
}

// ---------------------------------------------------------------------------
// Projected gradient ascent (100 iters), register-resident, barrier-free.
// ---------------------------------------------------------------------------
__global__ __launch_bounds__(64) void solve_kernel(const float* __restrict__ Wmat,
                                                   float* __restrict__ pred,
                                                   float* __restrict__ outp) {
  const int b = blockIdx.x;
  const int lane = threadIdx.x;
  float E[19], Ws[19], As[19];
  bool dg[19];
#pragma unroll
  for (int k = 0; k < 19; k++) {
    int e = lane + (k << 6);
    if (e < 1156) {
      int r = e / 34, c = e - r * 34;
      float w1 = Wmat[(size_t)b * 1156 + e];
      float w2 = Wmat[(size_t)b * 1156 + c * 34 + r];
      Ws[k] = 0.5f * (w1 + w2);
      As[k] = 0.5f * (((w1 != 0.f) ? 1.f : 0.f) + ((w2 != 0.f) ? 1.f : 0.f));
      dg[k] = (r == c && r < 4);
      E[k] = 0.5f;
    } else {
      Ws[k] = 0.f; As[k] = 0.f; dg[k] = false; E[k] = 0.f;
    }
  }
  for (int it = 0; it < 100; it++) {
    float ps = 0.f;
#pragma unroll
    for (int k = 0; k < 19; k++) ps += As[k] * E[k];
    float s = waveSum(ps);
    float dd = __shfl(E[0], 0, 64) + __shfl(E[0], 35, 64) +
               __shfl(E[1], 6, 64) + __shfl(E[1], 41, 64);
    float coef_s = (s > 6.f) ? 20.f * (s - 6.f) : 0.f;
    float coef_d = 20.f * (dd - 1.f);
#pragma unroll
    for (int k = 0; k < 19; k++) {
      float g = Ws[k] - coef_s * As[k] - (dg[k] ? coef_d : 0.f);
      E[k] = fminf(fmaxf(E[k] + 0.05f * g, 0.f), 1.f);
    }
  }
  float v0 = E[0], v1 = E[1];
  if (lane == 0)  { pred[b * 4 + 0] = v0; outp[1 + b * 4 + 0] = v0; }
  if (lane == 35) { pred[b * 4 + 1] = v0; outp[1 + b * 4 + 1] = v0; }
  if (lane == 6)  { pred[b * 4 + 2] = v1; outp[1 + b * 4 + 2] = v1; }
  if (lane == 41) { pred[b * 4 + 3] = v1; outp[1 + b * 4 + 3] = v1; }
}

// ---------------------------------------------------------------------------
// Final loss: out[0] = ce(log_softmax(pred), labels) + mse(sim, gold_sm)
// ---------------------------------------------------------------------------
__global__ __launch_bounds__(256) void loss_kernel(const float* __restrict__ sim,
                                                   const void* __restrict__ gold,
                                                   const float* __restrict__ pred,
                                                   const int* __restrict__ labels,
                                                   float* __restrict__ outp,
                                                   const int* __restrict__ F) {
  const int isb = *F;
  __shared__ float sh[4];
  const int tid = threadIdx.x;
  float local = 0.f;
  if (tid < 64) {
    float mx = -3.4e38f;
    for (int k = 0; k < 30; k++) mx = fmaxf(mx, ldf(gold, (size_t)tid * 30 + k, isb));
    float sum = 0.f;
    for (int k = 0; k < 30; k++) sum += expf(ldf(gold, (size_t)tid * 30 + k, isb) - mx);
    float inv = 1.f / sum;
    for (int k = 0; k < 30; k++) {
      float gsm = expf(ldf(gold, (size_t)tid * 30 + k, isb) - mx) * inv;
      float d = sim[(size_t)tid * 30 + k] - gsm;
      local += d * d;
    }
  }
  float mse = blockSum(local, sh) * (1.f / 1920.f);
  float cel = 0.f;
  if (tid < 16) {
    const float* f = pred + tid * 4;
    int lb = labels[tid] & 3;
    float mx = fmaxf(fmaxf(f[0], f[1]), fmaxf(f[2], f[3]));
    float lse = logf(expf(f[0] - mx) + expf(f[1] - mx) + expf(f[2] - mx) + expf(f[3] - mx));
    float lp = f[lb] - mx - lse;
    cel = -lp * (1.f / 16.f);
  }
  float ce = blockSum(cel, sh);
  if (tid == 0) outp[0] = ce + mse;
}

// ---------------------------------------------------------------------------
// Host orchestration
// ---------------------------------------------------------------------------
extern "C" void kernel_launch(void* const* d_in, const int* in_sizes, int n_in,
                              void* d_out, int out_size, void* d_ws, size_t ws_size,
                              hipStream_t stream) {
  (void)in_sizes; (void)n_in; (void)out_size;
  const int*  hyp_ids   = (const int*)d_in[0];
  const void* hyp_mask  = d_in[1];
  const void* fact_mask = d_in[2];
  const int*  fact_ids  = (const int*)d_in[3];
  const void* aa_ov     = d_in[5];
  const void* aa_sim_in = d_in[6];
  const void* qa_ov     = d_in[8];
  const void* qq        = d_in[11];
  const int*  labels    = (const int*)d_in[12];
  const void* gold      = d_in[13];
  const void* emb       = d_in[14];
  const void* Wqkv      = d_in[15];
  const void* bqkv      = d_in[16];
  const void* Wo        = d_in[17];
  const void* bo        = d_in[18];
  const void* ln1g      = d_in[19];
  const void* ln1b      = d_in[20];
  const void* Wff1      = d_in[21];
  const void* bff1      = d_in[22];
  const void* Wff2      = d_in[23];
  const void* bff2      = d_in[24];
  const void* ln2g      = d_in[25];
  const void* ln2b      = d_in[26];
  const void* scoreW    = d_in[27];
  const void* scoreB    = d_in[28];
  const void* absW      = d_in[29];
  const void* absB      = d_in[30];
  const void* p_aaov    = d_in[31];
  const void* p_aasim   = d_in[32];
  const void* p_qaov    = d_in[33];
  const void* p_qasim   = d_in[34];
  float* out = (float*)d_out;

  char* ws = (char*)d_ws;
  size_t off = 0;
  auto alloc = [&](size_t bytes) -> void* {
    void* p = ws + off;
    off += (bytes + 255) & ~(size_t)255;
    return p;
  };

  float* PRED = (float*)alloc(64ull * 4);
  int*   FLAG = (int*)alloc(256);
  float* SIM  = (float*)alloc(16ull * 120 * 4);
  float* QA   = (float*)alloc(16ull * 120 * 4);
  float* AASM = (float*)alloc(16ull * 900 * 4);
  float* AA   = (float*)alloc(16ull * 900 * 4);
  float* WMAT = (float*)alloc(16ull * 1156 * 4);
  float* FSEQ = (float*)alloc(480ull * 512 * 4);
  float* HSEQ = (float*)alloc(64ull * 512 * 4);
  u16* WT_QKV = (u16*)alloc(2ull * 1536 * 512 * 2);
  u16* WT_O   = (u16*)alloc(2ull * 512 * 512 * 2);
  u16* WT_F1  = (u16*)alloc(2ull * 2048 * 512 * 2);
  u16* WT_F2  = (u16*)alloc(2ull * 512 * 2048 * 2);

  // Dynamic chunking from ws_size (constant per process -> graph-safe).
  // 32768 = combined fact(30720)+hyp(2048) single-pass encode.
  const int opts_tok[6] = {32768, 30720, 15360, 10240, 6144, 3072};
  const int opts_nch[6] = {1, 1, 2, 3, 5, 10};
  int CH_TOK = 3072, NCH = 10;
  for (int i = 0; i < 6; i++) {
    size_t need = off + (size_t)opts_tok[i] * 7168 + 4096;
    if (need <= ws_size) { CH_TOK = opts_tok[i]; NCH = opts_nch[i]; break; }
  }
  u16* X   = (u16*)alloc((size_t)CH_TOK * 512 * 2);
  u16* BIG = (u16*)alloc((size_t)CH_TOK * 2048 * 2);
  u16* ATT = (u16*)alloc((size_t)CH_TOK * 512 * 2);
  u16* Y   = (u16*)alloc((size_t)CH_TOK * 512 * 2);

  detect_kernel<<<1, 1, 0, stream>>>(ln1g, FLAG);

  for (int l = 0; l < 2; l++) {
    transpose_kernel<<<dim3(48, 16), 256, 0, stream>>>(
        Wqkv, WT_QKV + (size_t)l * 1536 * 512, 512, 1536, (size_t)l * 512 * 1536, FLAG);
    transpose_kernel<<<dim3(16, 16), 256, 0, stream>>>(
        Wo, WT_O + (size_t)l * 512 * 512, 512, 512, (size_t)l * 512 * 512, FLAG);
    transpose_kernel<<<dim3(64, 16), 256, 0, stream>>>(
        Wff1, WT_F1 + (size_t)l * 2048 * 512, 512, 2048, (size_t)l * 512 * 2048, FLAG);
    transpose_kernel<<<dim3(16, 64), 256, 0, stream>>>(
        Wff2, WT_F2 + (size_t)l * 512 * 2048, 2048, 512, (size_t)l * 2048 * 512, FLAG);
  }

  if (CH_TOK >= 32768) {
    // ---- Combined fact+hyp encoder pass: M = 30720 + 2048 = 32768 ----
    const int M = 32768;
    const size_t HOFF = 30720;   // hyp token offset
    embed_kernel<<<30720, 256, 0, stream>>>(fact_ids, emb, X, 64, FLAG);
    embed_kernel<<<2048, 256, 0, stream>>>(hyp_ids, emb, X + HOFF * 512, 32, FLAG);
    for (int l = 0; l < 2; l++) {
      gemm_bt<0><<<dim3(12, M / 128), 256, 0, stream>>>(
          X, WT_QKV + (size_t)l * 1536 * 512, bqkv, BIG, M, 1536, 512,
          (size_t)l * 1536, FLAG);
      attn_kernel<<<480 * 8, 256, 0, stream>>>(BIG, ATT, 64);
      attn_kernel<<<64 * 8, 256, 0, stream>>>(BIG + HOFF * 1536, ATT + HOFF * 512, 32);
      gemm_bt<0><<<dim3(4, M / 128), 256, 0, stream>>>(
          ATT, WT_O + (size_t)l * 512 * 512, bo, Y, M, 512, 512,
          (size_t)l * 512, FLAG);
      add_ln_kernel<<<M, 256, 0, stream>>>(X, Y, ln1g, ln1b, (size_t)l * 512, FLAG);
      gemm_bt<1><<<dim3(16, M / 128), 256, 0, stream>>>(
          X, WT_F1 + (size_t)l * 2048 * 512, bff1, BIG, M, 2048, 512,
          (size_t)l * 2048, FLAG);
      gemm_bt<0><<<dim3(4, M / 128), 256, 0, stream>>>(
          BIG, WT_F2 + (size_t)l * 512 * 2048, bff2, Y, M, 512, 2048,
          (size_t)l * 512, FLAG);
      add_ln_kernel<<<M, 256, 0, stream>>>(X, Y, ln2g, ln2b, (size_t)l * 512, FLAG);
    }
    pool_kernel<<<480, 256, 0, stream>>>(X, fact_mask, FSEQ, 64, 0, FLAG);
    pool_kernel<<<64, 256, 0, stream>>>(X + HOFF * 512, hyp_mask, HSEQ, 32, 0, FLAG);
  } else {
    // ---- Fallback: chunked fact encode + separate hyp encode ----
    auto encode = [&](const int* ids, int nseq, int L, const void* mask,
                      size_t moff, float* pooled) {
      int M = nseq * L;   // multiple of 128
      embed_kernel<<<M, 256, 0, stream>>>(ids, emb, X, L, FLAG);
      for (int l = 0; l < 2; l++) {
        gemm_bt<0><<<dim3(12, M / 128), 256, 0, stream>>>(
            X, WT_QKV + (size_t)l * 1536 * 512, bqkv, BIG, M, 1536, 512,
            (size_t)l * 1536, FLAG);
        attn_kernel<<<nseq * 8, 256, 0, stream>>>(BIG, ATT, L);
        gemm_bt<0><<<dim3(4, M / 128), 256, 0, stream>>>(
            ATT, WT_O + (size_t)l * 512 * 512, bo, Y, M, 512, 512,
            (size_t)l * 512, FLAG);
        add_ln_kernel<<<M, 256, 0, stream>>>(X, Y, ln1g, ln1b, (size_t)l * 512, FLAG);
        gemm_bt<1><<<dim3(16, M / 128), 256, 0, stream>>>(
            X, WT_F1 + (size_t)l * 2048 * 512, bff1, BIG, M, 2048, 512,
            (size_t)l * 2048, FLAG);
        gemm_bt<0><<<dim3(4, M / 128), 256, 0, stream>>>(
            BIG, WT_F2 + (size_t)l * 512 * 2048, bff2, Y, M, 512, 2048,
            (size_t)l * 512, FLAG);
        add_ln_kernel<<<M, 256, 0, stream>>>(X, Y, ln2g, ln2b, (size_t)l * 512, FLAG);
      }
      pool_kernel<<<nseq, 256, 0, stream>>>(X, mask, pooled, L, moff, FLAG);
    };
    const int seq_per = 480 / NCH;
    for (int c = 0; c < NCH; c++) {
      encode(fact_ids + (size_t)c * seq_per * 64, seq_per, 64, fact_mask,
             (size_t)c * seq_per * 64, FSEQ + (size_t)c * seq_per * 512);
    }
    encode(hyp_ids, 64, 32, hyp_mask, 0, HSEQ);
  }

  pair_score_kernel<<<16 * 30 * 30, 64, 0, stream>>>(FSEQ, FSEQ, absW, absB, AA, 30, 30, FLAG);
  pair_score_kernel<<<16 * 4 * 30, 64, 0, stream>>>(HSEQ, FSEQ, scoreW, scoreB, QA, 4, 30, FLAG);
  aa_softmax_kernel<<<16, 256, 0, stream>>>(AA, AASM);
  qa_softmax_kernel<<<64, 64, 0, stream>>>(QA, SIM);

  edgew_kernel<<<(16 * 1156 + 255) / 256, 256, 0, stream>>>(
      aa_ov, aa_sim_in, qa_ov, qq, AASM, SIM, p_aaov, p_aasim, p_qaov, p_qasim,
      WMAT, FLAG);
  solve_kernel<<<16, 64, 0, stream>>>(WMAT, PRED, out);
  loss_kernel<<<1, 256, 0, stream>>>(SIM, gold, PRED, labels, out, FLAG);
}

// Round 5
// 990.209 us; speedup vs baseline: 1.4981x; 1.0329x over previous
//
#include <hip/hip_runtime.h>
#include <cstdint>
#include <cstddef>

// ---------------------------------------------------------------------------
// B=16 V=30522 D=512 H=8 DH=64 FF=2048 NC=4 NF=30 NN=34 FL=64 HL=32 L=2
// INPUT float tensors may be fp32 OR bf16 -- detected at runtime from ln1_g
// (all 1.0): fp32 -> first u32 == 0x3F800000 ; bf16 -> 0x3F803F80.
// OUTPUT: 65 FLOAT32 values = [loss, final_pred(16x4)].
// R13 change vs R12 (passed, 1022.8 us): GEMMs confirmed at m97-structure
// ceiling (FF1 892 TF, WRITE now exactly ideal) -> attack the ~560 us of
// non-GEMM time. All bit-exact:
//  (1) PE table precomputed once (same float exprs) -> embed is pure loads
//      (removes 16.7M on-device trig; guide Appendix B).
//  (2) Launch merges: embed 2->1, attn 2->1 per layer, pool 2->1,
//      transposes batched over layers via gridDim.z (8->4). 36->30 launches.
//  (3) attn softmax caches expf in Ss (halves transcendentals, same values).
// GEMM (gemm_bt: R8 rotation swizzle, R9 XCD swizzle, R12 write order) and
// add_ln untouched. Predicted: gemm top-5 unchanged; total ~975-995 us.
// ---------------------------------------------------------------------------

using u16 = unsigned short;

typedef __bf16 bf16x8 __attribute__((ext_vector_type(8)));
typedef float  floatx4 __attribute__((ext_vector_type(4)));

#if defined(__has_builtin)
#if __has_builtin(__builtin_amdgcn_global_load_lds)
#define USE_GLL 1
#endif
#endif

__device__ __forceinline__ float bf2f(u16 u) {
  return __uint_as_float(((unsigned)u) << 16);
}
__device__ __forceinline__ u16 f2bf(float f) {
  unsigned u = __float_as_uint(f);
  u += 0x7FFFu + ((u >> 16) & 1u);   // round-to-nearest-even
  return (u16)(u >> 16);
}
__device__ __forceinline__ float ldf(const void* p, size_t i, int isb) {
  return isb ? bf2f(((const u16*)p)[i]) : ((const float*)p)[i];
}

__device__ __forceinline__ float waveSum(float v) {
#pragma unroll
  for (int o = 32; o > 0; o >>= 1) v += __shfl_xor(v, o, 64);
  return v;
}
__device__ __forceinline__ float waveMax(float v) {
#pragma unroll
  for (int o = 32; o > 0; o >>= 1) v = fmaxf(v, __shfl_xor(v, o, 64));
  return v;
}
__device__ __forceinline__ float blockSum(float v, float* sh4) {
  v = waveSum(v);
  if ((threadIdx.x & 63) == 0) sh4[threadIdx.x >> 6] = v;
  __syncthreads();
  float r = sh4[0] + sh4[1] + sh4[2] + sh4[3];
  __syncthreads();
  return r;
}
__device__ __forceinline__ float blockMax(float v, float* sh4) {
  v = waveMax(v);
  if ((threadIdx.x & 63) == 0) sh4[threadIdx.x >> 6] = v;
  __syncthreads();
  float r = fmaxf(fmaxf(sh4[0], sh4[1]), fmaxf(sh4[2], sh4[3]));
  __syncthreads();
  return r;
}

// ---------------------------------------------------------------------------
__global__ void detect_kernel(const void* __restrict__ ln1g, int* __restrict__ flag) {
  unsigned u = *(const unsigned*)ln1g;
  *flag = (u == 0x3F800000u) ? 0 : 1;
}

// ---------------------------------------------------------------------------
// Positional-encoding table: petab[pos*512+d], pos<64. Same float exprs as
// the old embed (bit-identical results).
// ---------------------------------------------------------------------------
__global__ __launch_bounds__(256) void pe_kernel(float* __restrict__ petab) {
  const int pos = blockIdx.x;
  const float LOG1E4_OVER_D = 9.210340371976184f / 512.0f;
  for (int d = threadIdx.x; d < 512; d += 256) {
    int i2 = d & ~1;
    float ang = (float)pos * expf(-(float)i2 * LOG1E4_OVER_D);
    petab[pos * 512 + d] = (d & 1) ? cosf(ang) : sinf(ang);
  }
}

// ---------------------------------------------------------------------------
// Transpose + ->bf16: src elements [eoff + k*N + n] -> dst[n*K + k].
// Batched over layers via blockIdx.z (srcz/dstz element strides).
// ---------------------------------------------------------------------------
__global__ __launch_bounds__(256) void transpose_kernel(const void* __restrict__ src,
                                                        u16* __restrict__ dst,
                                                        int K, int N,
                                                        size_t srcz, size_t dstz,
                                                        const int* __restrict__ F) {
  const int isb = *F;
  __shared__ u16 tile[32][33];
  size_t eoff = (size_t)blockIdx.z * srcz;
  u16* d = dst + (size_t)blockIdx.z * dstz;
  int bx = blockIdx.x, by = blockIdx.y;
  int tx = threadIdx.x & 31, ty = threadIdx.x >> 5;
  for (int i = ty; i < 32; i += 8)
    tile[i][tx] = f2bf(ldf(src, eoff + (size_t)(by * 32 + i) * N + bx * 32 + tx, isb));
  __syncthreads();
  for (int i = ty; i < 32; i += 8)
    d[(size_t)(bx * 32 + i) * K + by * 32 + tx] = tile[tx][i];
}

// ---------------------------------------------------------------------------
// Embedding + positional encoding (table-driven). Generic (fallback path).
// ---------------------------------------------------------------------------
__global__ __launch_bounds__(256) void embed_kernel(const int* __restrict__ ids,
                                                    const void* __restrict__ emb,
                                                    u16* __restrict__ x, int L,
                                                    const float* __restrict__ petab,
                                                    const int* __restrict__ F) {
  const int isb = *F;
  int tok = blockIdx.x;
  int pos = tok % L;
  int id = ids[tok];
  for (int d = threadIdx.x; d < 512; d += 256) {
    float e = ldf(emb, (size_t)id * 512 + d, isb) * 22.62741699796952f;
    x[(size_t)tok * 512 + d] = f2bf(e + petab[pos * 512 + d]);
  }
}

// Merged fact+hyp embed: tok<30720 -> fact (L=64); else hyp (L=32).
__global__ __launch_bounds__(256) void embed2_kernel(const int* __restrict__ fids,
                                                     const int* __restrict__ hids,
                                                     const void* __restrict__ emb,
                                                     u16* __restrict__ x,
                                                     const float* __restrict__ petab,
                                                     const int* __restrict__ F) {
  const int isb = *F;
  int tok = blockIdx.x;
  int id, pos;
  if (tok < 30720) { id = fids[tok]; pos = tok & 63; }
  else             { int t2 = tok - 30720; id = hids[t2]; pos = t2 & 31; }
  for (int d = threadIdx.x; d < 512; d += 256) {
    float e = ldf(emb, (size_t)id * 512 + d, isb) * 22.62741699796952f;
    x[(size_t)tok * 512 + d] = f2bf(e + petab[pos * 512 + d]);
  }
}

// ---------------------------------------------------------------------------
// GEMM: C[M][N] = A[M][K] @ Bt[N][K]^T + bias[boff..]  (optional relu)
// bf16 in, fp32 MFMA accumulate, bf16 out. 128x128 tile, BK=64, 256 threads.
// LDS layout: row r holds its eight 16B chunks ROTATED: global chunk q at
// position (q + r) & 7 (0 bank conflicts). XCD-chunked bijective swizzle of
// (bm,bn). Epilogue writes row-major (ni innermost): full 128B lines.
// ---------------------------------------------------------------------------
template <int RELU>
__global__ __launch_bounds__(256, 2) void gemm_bt(const u16* __restrict__ A,
                                                  const u16* __restrict__ Bt,
                                                  const void* __restrict__ bias,
                                                  u16* __restrict__ C,
                                                  int M, int N, int K, size_t boff,
                                                  const int* __restrict__ F) {
  const int isb = *F;
  __shared__ __align__(16) u16 As[128 * 64];
  __shared__ __align__(16) u16 Bs[128 * 64];
  const int tid = threadIdx.x;
  const int lane = tid & 63;
  const int wave = tid >> 6;
  const int wm = wave >> 1, wn = wave & 1;
  const int l15 = lane & 15, quad = lane >> 4;

  // --- XCD-aware bijective remap (T1, m192/m204) ---
  const int nwg = gridDim.x * gridDim.y;
  const int hw  = blockIdx.y * gridDim.x + blockIdx.x;
  int lg;
  if ((nwg & 7) == 0) {
    lg = (hw & 7) * (nwg >> 3) + (hw >> 3);
  } else {
    int q = nwg >> 3, r = nwg & 7;
    int xcd = hw & 7, j = hw >> 3;
    lg = (xcd < r ? xcd * (q + 1) : r * (q + 1) + (xcd - r) * q) + j;
  }
  const int bm = lg / gridDim.x;
  const int bn = lg - bm * gridDim.x;

  floatx4 acc[4][4];
#pragma unroll
  for (int i = 0; i < 4; i++)
#pragma unroll
    for (int j = 0; j < 4; j++) acc[i][j] = (floatx4){0.f, 0.f, 0.f, 0.f};

  const u16* Abase = A + (size_t)bm * 128 * K;
  const u16* Bbase = Bt + (size_t)bn * 128 * K;

  for (int kt = 0; kt < K; kt += 64) {
#pragma unroll
    for (int i = 0; i < 4; i++) {
      int c = i * 256 + tid;             // LDS chunk id 0..1023 (lane-contig)
      int row = c >> 3, p = c & 7;
      int col = (((p - row) & 7)) * 8;   // rotated source chunk (same 128B line)
      const u16* ga = &Abase[(size_t)row * K + kt + col];
      const u16* gb = &Bbase[(size_t)row * K + kt + col];
#ifdef USE_GLL
      __builtin_amdgcn_global_load_lds(
          (const __attribute__((address_space(1))) void*)ga,
          (__attribute__((address_space(3))) void*)&As[c * 8], 16, 0, 0);
      __builtin_amdgcn_global_load_lds(
          (const __attribute__((address_space(1))) void*)gb,
          (__attribute__((address_space(3))) void*)&Bs[c * 8], 16, 0, 0);
#else
      *(uint4*)&As[c * 8] = *(const uint4*)ga;
      *(uint4*)&Bs[c * 8] = *(const uint4*)gb;
#endif
    }
    __syncthreads();
#pragma unroll
    for (int ks = 0; ks < 2; ks++) {
      bf16x8 af[4], bfr[4];
#pragma unroll
      for (int mi = 0; mi < 4; mi++) {
        int ra = wm * 64 + mi * 16 + l15;
        int q = ks * 4 + quad;
        af[mi] = *(const bf16x8*)&As[ra * 64 + ((q + ra) & 7) * 8];
      }
#pragma unroll
      for (int ni = 0; ni < 4; ni++) {
        int rb = wn * 64 + ni * 16 + l15;
        int q = ks * 4 + quad;
        bfr[ni] = *(const bf16x8*)&Bs[rb * 64 + ((q + rb) & 7) * 8];
      }
#pragma unroll
      for (int mi = 0; mi < 4; mi++)
#pragma unroll
        for (int ni = 0; ni < 4; ni++)
          acc[mi][ni] = __builtin_amdgcn_mfma_f32_16x16x32_bf16(af[mi], bfr[ni], acc[mi][ni], 0, 0, 0);
    }
    __syncthreads();
  }

  // Epilogue: ni innermost -> each 128B row segment written back-to-back.
  float bv[4];
  const int gcb = bn * 128 + wn * 64 + l15;
#pragma unroll
  for (int ni = 0; ni < 4; ni++) bv[ni] = ldf(bias, boff + gcb + ni * 16, isb);
#pragma unroll
  for (int mi = 0; mi < 4; mi++) {
#pragma unroll
    for (int r = 0; r < 4; r++) {
      int grow = bm * 128 + wm * 64 + mi * 16 + quad * 4 + r;
      size_t rb = (size_t)grow * N + gcb;
#pragma unroll
      for (int ni = 0; ni < 4; ni++) {
        float v = acc[mi][ni][r] + bv[ni];
        if (RELU) v = fmaxf(v, 0.f);
        C[rb + ni * 16] = f2bf(v);
      }
    }
  }
}

// ---------------------------------------------------------------------------
// MFMA attention: one block per (seq, head), 256 threads (2x2 wave grid).
// LDS row stride 72 elems (144 B) -> fragment reads are 2-way (free).
// Two sub-dispatches merged: blocks [0,nblk1) use (qkv,o,L); rest (qkv2,o2,L2).
// Softmax caches expf values in Ss (bit-identical, half the transcendentals).
// ---------------------------------------------------------------------------
__global__ __launch_bounds__(256) void attn_kernel(const u16* __restrict__ qkv,
                                                   u16* __restrict__ o, int L,
                                                   int nblk1,
                                                   const u16* __restrict__ qkv2,
                                                   u16* __restrict__ o2, int L2) {
  int bid = blockIdx.x;
  if (bid >= nblk1) { qkv = qkv2; o = o2; L = L2; bid -= nblk1; }
  const int h = bid & 7;
  const int s = bid >> 3;
  __shared__ __align__(16) u16 Qs[64 * 72];   // Q, later reused as P
  __shared__ __align__(16) u16 Ks[64 * 72];
  __shared__ __align__(16) u16 Vt[64 * 72];   // V^T: [d][t]
  __shared__ float Ss[64 * 66];
  const int tid = threadIdx.x;
  const int lane = tid & 63;
  const int wave = tid >> 6;
  const int wm = wave >> 1, wn = wave & 1;
  const int l15 = lane & 15, quad = lane >> 4;
  const int base = s * L;

  for (int idx = tid; idx < 512; idx += 256) {
    int t = idx >> 3, d8 = (idx & 7) * 8;
    if (t < L) {
      size_t g = (size_t)(base + t) * 1536 + h * 64 + d8;
      *(uint4*)&Qs[t * 72 + d8] = *(const uint4*)&qkv[g];
      *(uint4*)&Ks[t * 72 + d8] = *(const uint4*)&qkv[g + 512];
      u16 vv[8];
      *(uint4*)vv = *(const uint4*)&qkv[g + 1024];
#pragma unroll
      for (int i = 0; i < 8; i++) Vt[(d8 + i) * 72 + t] = vv[i];
    } else {
      uint4 z = {0u, 0u, 0u, 0u};
      *(uint4*)&Qs[t * 72 + d8] = z;
      *(uint4*)&Ks[t * 72 + d8] = z;
#pragma unroll
      for (int i = 0; i < 8; i++) Vt[(d8 + i) * 72 + t] = 0;
    }
  }
  __syncthreads();

  {
    floatx4 acc[2][2];
#pragma unroll
    for (int mi = 0; mi < 2; mi++)
#pragma unroll
      for (int ni = 0; ni < 2; ni++) acc[mi][ni] = (floatx4){0.f, 0.f, 0.f, 0.f};
#pragma unroll
    for (int ks = 0; ks < 2; ks++) {
      bf16x8 af[2], bfr[2];
#pragma unroll
      for (int mi = 0; mi < 2; mi++)
        af[mi] = *(const bf16x8*)&Qs[(wm * 32 + mi * 16 + l15) * 72 + ks * 32 + quad * 8];
#pragma unroll
      for (int ni = 0; ni < 2; ni++)
        bfr[ni] = *(const bf16x8*)&Ks[(wn * 32 + ni * 16 + l15) * 72 + ks * 32 + quad * 8];
#pragma unroll
      for (int mi = 0; mi < 2; mi++)
#pragma unroll
        for (int ni = 0; ni < 2; ni++)
          acc[mi][ni] = __builtin_amdgcn_mfma_f32_16x16x32_bf16(af[mi], bfr[ni], acc[mi][ni], 0, 0, 0);
    }
#pragma unroll
    for (int mi = 0; mi < 2; mi++)
#pragma unroll
      for (int ni = 0; ni < 2; ni++)
#pragma unroll
        for (int r = 0; r < 4; r++)
          Ss[(wm * 32 + mi * 16 + quad * 4 + r) * 66 + wn * 32 + ni * 16 + l15] =
              acc[mi][ni][r] * 0.125f;
  }
  __syncthreads();

  {
    int r = tid >> 2, sub = tid & 3;
    int j0 = sub * 16;
    float mx = -3.4e38f;
    if (r < L)
      for (int j = j0; j < j0 + 16; j++)
        if (j < L) mx = fmaxf(mx, Ss[r * 66 + j]);
    mx = fmaxf(mx, __shfl_xor(mx, 1, 64));
    mx = fmaxf(mx, __shfl_xor(mx, 2, 64));
    float sum = 0.f;
    if (r < L)
      for (int j = j0; j < j0 + 16; j++)
        if (j < L) { float e = expf(Ss[r * 66 + j] - mx); Ss[r * 66 + j] = e; sum += e; }
    sum += __shfl_xor(sum, 1, 64);
    sum += __shfl_xor(sum, 2, 64);
    float inv = 1.f / sum;
    if (r < L)
      for (int j = j0; j < j0 + 16; j++)
        Qs[r * 72 + j] = (j < L) ? f2bf(Ss[r * 66 + j] * inv) : (u16)0;
  }
  __syncthreads();

  {
    floatx4 acc[2][2];
#pragma unroll
    for (int mi = 0; mi < 2; mi++)
#pragma unroll
      for (int ni = 0; ni < 2; ni++) acc[mi][ni] = (floatx4){0.f, 0.f, 0.f, 0.f};
#pragma unroll
    for (int ks = 0; ks < 2; ks++) {
      bf16x8 af[2], bfr[2];
#pragma unroll
      for (int mi = 0; mi < 2; mi++)
        af[mi] = *(const bf16x8*)&Qs[(wm * 32 + mi * 16 + l15) * 72 + ks * 32 + quad * 8];
#pragma unroll
      for (int ni = 0; ni < 2; ni++)
        bfr[ni] = *(const bf16x8*)&Vt[(wn * 32 + ni * 16 + l15) * 72 + ks * 32 + quad * 8];
#pragma unroll
      for (int mi = 0; mi < 2; mi++)
#pragma unroll
        for (int ni = 0; ni < 2; ni++)
          acc[mi][ni] = __builtin_amdgcn_mfma_f32_16x16x32_bf16(af[mi], bfr[ni], acc[mi][ni], 0, 0, 0);
    }
#pragma unroll
    for (int mi = 0; mi < 2; mi++) {
#pragma unroll
      for (int r = 0; r < 4; r++) {
        int t = wm * 32 + mi * 16 + quad * 4 + r;
        if (t < L) {
#pragma unroll
          for (int ni = 0; ni < 2; ni++) {
            int d = wn * 32 + ni * 16 + l15;
            o[(size_t)(base + t) * 512 + h * 64 + d] = f2bf(acc[mi][ni][r]);
          }
        }
      }
    }
  }
}

// ---------------------------------------------------------------------------
// x = LayerNorm(x + y) * g[eoff..] + b[eoff..]   (packed 2x bf16 per thread)
// ---------------------------------------------------------------------------
__global__ __launch_bounds__(256) void add_ln_kernel(u16* __restrict__ x,
                                                     const u16* __restrict__ y,
                                                     const void* __restrict__ g,
                                                     const void* __restrict__ b,
                                                     size_t eoff,
                                                     const int* __restrict__ F) {
  const int isb = *F;
  const int row = blockIdx.x, tid = threadIdx.x;
  __shared__ float sh[4];
  size_t o0 = (size_t)row * 512 + tid * 2;
  unsigned xv = *(const unsigned*)&x[o0];
  unsigned yv = *(const unsigned*)&y[o0];
  float v0 = bf2f((u16)xv) + bf2f((u16)yv);
  float v1 = bf2f((u16)(xv >> 16)) + bf2f((u16)(yv >> 16));
  float mean = blockSum(v0 + v1, sh) * (1.f / 512.f);
  float d0 = v0 - mean, d1 = v1 - mean;
  float var = blockSum(d0 * d0 + d1 * d1, sh) * (1.f / 512.f);
  float rstd = rsqrtf(var + 1e-5f);
  float g0 = ldf(g, eoff + tid * 2, isb),     g1 = ldf(g, eoff + tid * 2 + 1, isb);
  float b0 = ldf(b, eoff + tid * 2, isb),     b1 = ldf(b, eoff + tid * 2 + 1, isb);
  unsigned r0 = f2bf(d0 * rstd * g0 + b0);
  unsigned r1 = f2bf(d1 * rstd * g1 + b1);
  *(unsigned*)&x[o0] = r0 | (r1 << 16);
}

// ---------------------------------------------------------------------------
// Masked mean pool (generic, fallback); mask elements at [moff + s*L + t].
// ---------------------------------------------------------------------------
__global__ __launch_bounds__(256) void pool_kernel(const u16* __restrict__ x,
                                                   const void* __restrict__ mask,
                                                   float* __restrict__ pooled, int L,
                                                   size_t moff,
                                                   const int* __restrict__ F) {
  const int isb = *F;
  const int s = blockIdx.x;
  float msum = 0.f;
  for (int t = 0; t < L; t++) msum += ldf(mask, moff + s * L + t, isb);
  float inv = 1.f / fmaxf(msum, 1e-9f);
  for (int d = threadIdx.x; d < 512; d += 256) {
    float acc = 0.f;
    for (int t = 0; t < L; t++)
      acc += bf2f(x[(size_t)(s * L + t) * 512 + d]) * ldf(mask, moff + s * L + t, isb);
    pooled[(size_t)s * 512 + d] = acc * inv;
  }
}

// Merged fact+hyp pool: blocks [0,480) facts (L=64); [480,544) hyps (L=32).
__global__ __launch_bounds__(256) void pool2_kernel(const u16* __restrict__ xf,
                                                    const void* __restrict__ fmask,
                                                    float* __restrict__ fpool,
                                                    const u16* __restrict__ xh,
                                                    const void* __restrict__ hmask,
                                                    float* __restrict__ hpool,
                                                    const int* __restrict__ F) {
  const int isb = *F;
  const u16* x; const void* mask; float* pooled; int L, s;
  if (blockIdx.x < 480) { x = xf; mask = fmask; pooled = fpool; L = 64; s = blockIdx.x; }
  else                  { x = xh; mask = hmask; pooled = hpool; L = 32; s = blockIdx.x - 480; }
  float msum = 0.f;
  for (int t = 0; t < L; t++) msum += ldf(mask, (size_t)s * L + t, isb);
  float inv = 1.f / fmaxf(msum, 1e-9f);
  for (int d = threadIdx.x; d < 512; d += 256) {
    float acc = 0.f;
    for (int t = 0; t < L; t++)
      acc += bf2f(x[(size_t)(s * L + t) * 512 + d]) * ldf(mask, (size_t)s * L + t, isb);
    pooled[(size_t)s * 512 + d] = acc * inv;
  }
}

// ---------------------------------------------------------------------------
// Pairwise score
// ---------------------------------------------------------------------------
__global__ __launch_bounds__(64) void pair_score_kernel(const float* __restrict__ X,
                                                        const float* __restrict__ Y,
                                                        const void* __restrict__ Wv,
                                                        const void* __restrict__ bscal,
                                                        float* __restrict__ outp,
                                                        int NI, int NJ,
                                                        const int* __restrict__ F) {
  const int isb = *F;
  int gid = blockIdx.x;
  int j = gid % NJ;
  int t = gid / NJ;
  int i = t % NI;
  int b = t / NI;
  const float* xv = X + ((size_t)b * NI + i) * 512;
  const float* yv = Y + ((size_t)b * NJ + j) * 512;
  int l = threadIdx.x;
  float p = 0.f;
  for (int d = l; d < 512; d += 64) {
    float xi = xv[d], yj = yv[d];
    p += ldf(Wv, d, isb) * yj + ldf(Wv, 512 + d, isb) * xi +
         ldf(Wv, 1024 + d, isb) * fabsf(yj - xi) + ldf(Wv, 1536 + d, isb) * xi * yj;
  }
  p = waveSum(p);
  if (l == 0) outp[gid] = p + ldf(bscal, 0, isb);
}

__global__ __launch_bounds__(256) void aa_softmax_kernel(const float* __restrict__ aa,
                                                         float* __restrict__ aasm) {
  const int b = blockIdx.x;
  const float* src = aa + (size_t)b * 900;
  float* dst = aasm + (size_t)b * 900;
  __shared__ float sh[4];
  int tid = threadIdx.x;
  float mx = -3.4e38f;
  for (int i = tid; i < 900; i += 256) mx = fmaxf(mx, src[i]);
  mx = blockMax(mx, sh);
  float sum = 0.f;
  for (int i = tid; i < 900; i += 256) sum += expf(src[i] - mx);
  sum = blockSum(sum, sh);
  float inv = 1.f / sum;
  for (int i = tid; i < 900; i += 256) {
    int r = i / 30, c = i - r * 30;
    dst[i] = (r == c) ? 0.f : expf(src[i] - mx) * inv;
  }
}

__global__ __launch_bounds__(64) void qa_softmax_kernel(const float* __restrict__ qa,
                                                        float* __restrict__ sim) {
  int g = blockIdx.x;
  int l = threadIdx.x;
  float v = (l < 30) ? qa[(size_t)g * 30 + l] : -3.4e38f;
  float mx = waveMax(v);
  float e = (l < 30) ? expf(v - mx) : 0.f;
  float s = waveSum(e);
  if (l < 30) sim[(size_t)g * 30 + l] = e / s;
}

// ---------------------------------------------------------------------------
// Edge weights
// ---------------------------------------------------------------------------
__global__ __launch_bounds__(256) void edgew_kernel(const void* __restrict__ aaov,
                                                    const void* __restrict__ aasim_in,
                                                    const void* __restrict__ qaov,
                                                    const void* __restrict__ qq,
                                                    const float* __restrict__ aasm,
                                                    const float* __restrict__ sim,
                                                    const void* __restrict__ p1,
                                                    const void* __restrict__ p2,
                                                    const void* __restrict__ p3,
                                                    const void* __restrict__ p4,
                                                    float* __restrict__ Wout,
                                                    const int* __restrict__ F) {
  const int isb = *F;
  int e = blockIdx.x * 256 + threadIdx.x;
  if (e >= 16 * 1156) return;
  int b = e / 1156;
  int rem = e - b * 1156;
  int r = rem / 34, c = rem - r * 34;
  float aas;
  if (r >= 4 && c >= 4) aas = aasm[(size_t)b * 900 + (r - 4) * 30 + (c - 4)];
  else                  aas = ldf(aasim_in, e, isb);
  float qas = 0.f;
  if (r >= 4 && c < 4)      qas = sim[((size_t)b * 4 + c) * 30 + (r - 4)];
  else if (r < 4 && c >= 4) qas = sim[((size_t)b * 4 + r) * 30 + (c - 4)];
  float w = -ldf(p1, 0, isb) * ldf(aaov, e, isb) + ldf(p2, 0, isb) * aas +
            ldf(p3, 0, isb) * ldf(qaov, e, isb) + ldf(p4, 0, isb) * qas +
            ldf(qq, e, isb);
  Wout[e] = w;
}

// ---------------------------------------------------------------------------
// Projected gradient ascent (100 iters), register-resident, barrier-free.
// ---------------------------------------------------------------------------
__global__ __launch_bounds__(64) void solve_kernel(const float* __restrict__ Wmat,
                                                   float* __restrict__ pred,
                                                   float* __restrict__ outp) {
  const int b = blockIdx.x;
  const int lane = threadIdx.x;
  float E[19], Ws[19], As[19];
  bool dg[19];
#pragma unroll
  for (int k = 0; k < 19; k++) {
    int e = lane + (k << 6);
    if (e < 1156) {
      int r = e / 34, c = e - r * 34;
      float w1 = Wmat[(size_t)b * 1156 + e];
      float w2 = Wmat[(size_t)b * 1156 + c * 34 + r];
      Ws[k] = 0.5f * (w1 + w2);
      As[k] = 0.5f * (((w1 != 0.f) ? 1.f : 0.f) + ((w2 != 0.f) ? 1.f : 0.f));
      dg[k] = (r == c && r < 4);
      E[k] = 0.5f;
    } else {
      Ws[k] = 0.f; As[k] = 0.f; dg[k] = false; E[k] = 0.f;
    }
  }
  for (int it = 0; it < 100; it++) {
    float ps = 0.f;
#pragma unroll
    for (int k = 0; k < 19; k++) ps += As[k] * E[k];
    float s = waveSum(ps);
    float dd = __shfl(E[0], 0, 64) + __shfl(E[0], 35, 64) +
               __shfl(E[1], 6, 64) + __shfl(E[1], 41, 64);
    float coef_s = (s > 6.f) ? 20.f * (s - 6.f) : 0.f;
    float coef_d = 20.f * (dd - 1.f);
#pragma unroll
    for (int k = 0; k < 19; k++) {
      float g = Ws[k] - coef_s * As[k] - (dg[k] ? coef_d : 0.f);
      E[k] = fminf(fmaxf(E[k] + 0.05f * g, 0.f), 1.f);
    }
  }
  float v0 = E[0], v1 = E[1];
  if (lane == 0)  { pred[b * 4 + 0] = v0; outp[1 + b * 4 + 0] = v0; }
  if (lane == 35) { pred[b * 4 + 1] = v0; outp[1 + b * 4 + 1] = v0; }
  if (lane == 6)  { pred[b * 4 + 2] = v1; outp[1 + b * 4 + 2] = v1; }
  if (lane == 41) { pred[b * 4 + 3] = v1; outp[1 + b * 4 + 3] = v1; }
}

// ---------------------------------------------------------------------------
// Final loss: out[0] = ce(log_softmax(pred), labels) + mse(sim, gold_sm)
// ---------------------------------------------------------------------------
__global__ __launch_bounds__(256) void loss_kernel(const float* __restrict__ sim,
                                                   const void* __restrict__ gold,
                                                   const float* __restrict__ pred,
                                                   const int* __restrict__ labels,
                                                   float* __restrict__ outp,
                                                   const int* __restrict__ F) {
  const int isb = *F;
  __shared__ float sh[4];
  const int tid = threadIdx.x;
  float local = 0.f;
  if (tid < 64) {
    float mx = -3.4e38f;
    for (int k = 0; k < 30; k++) mx = fmaxf(mx, ldf(gold, (size_t)tid * 30 + k, isb));
    float sum = 0.f;
    for (int k = 0; k < 30; k++) sum += expf(ldf(gold, (size_t)tid * 30 + k, isb) - mx);
    float inv = 1.f / sum;
    for (int k = 0; k < 30; k++) {
      float gsm = expf(ldf(gold, (size_t)tid * 30 + k, isb) - mx) * inv;
      float d = sim[(size_t)tid * 30 + k] - gsm;
      local += d * d;
    }
  }
  float mse = blockSum(local, sh) * (1.f / 1920.f);
  float cel = 0.f;
  if (tid < 16) {
    const float* f = pred + tid * 4;
    int lb = labels[tid] & 3;
    float mx = fmaxf(fmaxf(f[0], f[1]), fmaxf(f[2], f[3]));
    float lse = logf(expf(f[0] - mx) + expf(f[1] - mx) + expf(f[2] - mx) + expf(f[3] - mx));
    float lp = f[lb] - mx - lse;
    cel = -lp * (1.f / 16.f);
  }
  float ce = blockSum(cel, sh);
  if (tid == 0) outp[0] = ce + mse;
}

// ---------------------------------------------------------------------------
// Host orchestration
// ---------------------------------------------------------------------------
extern "C" void kernel_launch(void* const* d_in, const int* in_sizes, int n_in,
                              void* d_out, int out_size, void* d_ws, size_t ws_size,
                              hipStream_t stream) {
  (void)in_sizes; (void)n_in; (void)out_size;
  const int*  hyp_ids   = (const int*)d_in[0];
  const void* hyp_mask  = d_in[1];
  const void* fact_mask = d_in[2];
  const int*  fact_ids  = (const int*)d_in[3];
  const void* aa_ov     = d_in[5];
  const void* aa_sim_in = d_in[6];
  const void* qa_ov     = d_in[8];
  const void* qq        = d_in[11];
  const int*  labels    = (const int*)d_in[12];
  const void* gold      = d_in[13];
  const void* emb       = d_in[14];
  const void* Wqkv      = d_in[15];
  const void* bqkv      = d_in[16];
  const void* Wo        = d_in[17];
  const void* bo        = d_in[18];
  const void* ln1g      = d_in[19];
  const void* ln1b      = d_in[20];
  const void* Wff1      = d_in[21];
  const void* bff1      = d_in[22];
  const void* Wff2      = d_in[23];
  const void* bff2      = d_in[24];
  const void* ln2g      = d_in[25];
  const void* ln2b      = d_in[26];
  const void* scoreW    = d_in[27];
  const void* scoreB    = d_in[28];
  const void* absW      = d_in[29];
  const void* absB      = d_in[30];
  const void* p_aaov    = d_in[31];
  const void* p_aasim   = d_in[32];
  const void* p_qaov    = d_in[33];
  const void* p_qasim   = d_in[34];
  float* out = (float*)d_out;

  char* ws = (char*)d_ws;
  size_t off = 0;
  auto alloc = [&](size_t bytes) -> void* {
    void* p = ws + off;
    off += (bytes + 255) & ~(size_t)255;
    return p;
  };

  float* PRED = (float*)alloc(64ull * 4);
  int*   FLAG = (int*)alloc(256);
  float* SIM  = (float*)alloc(16ull * 120 * 4);
  float* QA   = (float*)alloc(16ull * 120 * 4);
  float* AASM = (float*)alloc(16ull * 900 * 4);
  float* AA   = (float*)alloc(16ull * 900 * 4);
  float* WMAT = (float*)alloc(16ull * 1156 * 4);
  float* FSEQ = (float*)alloc(480ull * 512 * 4);
  float* HSEQ = (float*)alloc(64ull * 512 * 4);
  float* PETAB= (float*)alloc(64ull * 512 * 4);
  u16* WT_QKV = (u16*)alloc(2ull * 1536 * 512 * 2);
  u16* WT_O   = (u16*)alloc(2ull * 512 * 512 * 2);
  u16* WT_F1  = (u16*)alloc(2ull * 2048 * 512 * 2);
  u16* WT_F2  = (u16*)alloc(2ull * 512 * 2048 * 2);

  // Dynamic chunking from ws_size (constant per process -> graph-safe).
  // 32768 = combined fact(30720)+hyp(2048) single-pass encode.
  const int opts_tok[6] = {32768, 30720, 15360, 10240, 6144, 3072};
  const int opts_nch[6] = {1, 1, 2, 3, 5, 10};
  int CH_TOK = 3072, NCH = 10;
  for (int i = 0; i < 6; i++) {
    size_t need = off + (size_t)opts_tok[i] * 7168 + 4096;
    if (need <= ws_size) { CH_TOK = opts_tok[i]; NCH = opts_nch[i]; break; }
  }
  u16* X   = (u16*)alloc((size_t)CH_TOK * 512 * 2);
  u16* BIG = (u16*)alloc((size_t)CH_TOK * 2048 * 2);
  u16* ATT = (u16*)alloc((size_t)CH_TOK * 512 * 2);
  u16* Y   = (u16*)alloc((size_t)CH_TOK * 512 * 2);

  detect_kernel<<<1, 1, 0, stream>>>(ln1g, FLAG);
  pe_kernel<<<64, 256, 0, stream>>>(PETAB);

  // Weight transposes, batched over the 2 layers via gridDim.z.
  transpose_kernel<<<dim3(48, 16, 2), 256, 0, stream>>>(
      Wqkv, WT_QKV, 512, 1536, 512ull * 1536, 1536ull * 512, FLAG);
  transpose_kernel<<<dim3(16, 16, 2), 256, 0, stream>>>(
      Wo, WT_O, 512, 512, 512ull * 512, 512ull * 512, FLAG);
  transpose_kernel<<<dim3(64, 16, 2), 256, 0, stream>>>(
      Wff1, WT_F1, 512, 2048, 512ull * 2048, 2048ull * 512, FLAG);
  transpose_kernel<<<dim3(16, 64, 2), 256, 0, stream>>>(
      Wff2, WT_F2, 2048, 512, 2048ull * 512, 512ull * 2048, FLAG);

  if (CH_TOK >= 32768) {
    // ---- Combined fact+hyp encoder pass: M = 30720 + 2048 = 32768 ----
    const int M = 32768;
    const size_t HOFF = 30720;   // hyp token offset
    embed2_kernel<<<M, 256, 0, stream>>>(fact_ids, hyp_ids, emb, X, PETAB, FLAG);
    for (int l = 0; l < 2; l++) {
      gemm_bt<0><<<dim3(12, M / 128), 256, 0, stream>>>(
          X, WT_QKV + (size_t)l * 1536 * 512, bqkv, BIG, M, 1536, 512,
          (size_t)l * 1536, FLAG);
      attn_kernel<<<480 * 8 + 64 * 8, 256, 0, stream>>>(
          BIG, ATT, 64, 480 * 8, BIG + HOFF * 1536, ATT + HOFF * 512, 32);
      gemm_bt<0><<<dim3(4, M / 128), 256, 0, stream>>>(
          ATT, WT_O + (size_t)l * 512 * 512, bo, Y, M, 512, 512,
          (size_t)l * 512, FLAG);
      add_ln_kernel<<<M, 256, 0, stream>>>(X, Y, ln1g, ln1b, (size_t)l * 512, FLAG);
      gemm_bt<1><<<dim3(16, M / 128), 256, 0, stream>>>(
          X, WT_F1 + (size_t)l * 2048 * 512, bff1, BIG, M, 2048, 512,
          (size_t)l * 2048, FLAG);
      gemm_bt<0><<<dim3(4, M / 128), 256, 0, stream>>>(
          BIG, WT_F2 + (size_t)l * 512 * 2048, bff2, Y, M, 512, 2048,
          (size_t)l * 512, FLAG);
      add_ln_kernel<<<M, 256, 0, stream>>>(X, Y, ln2g, ln2b, (size_t)l * 512, FLAG);
    }
    pool2_kernel<<<544, 256, 0, stream>>>(X, fact_mask, FSEQ,
                                          X + HOFF * 512, hyp_mask, HSEQ, FLAG);
  } else {
    // ---- Fallback: chunked fact encode + separate hyp encode ----
    auto encode = [&](const int* ids, int nseq, int L, const void* mask,
                      size_t moff, float* pooled) {
      int M = nseq * L;   // multiple of 128
      embed_kernel<<<M, 256, 0, stream>>>(ids, emb, X, L, PETAB, FLAG);
      for (int l = 0; l < 2; l++) {
        gemm_bt<0><<<dim3(12, M / 128), 256, 0, stream>>>(
            X, WT_QKV + (size_t)l * 1536 * 512, bqkv, BIG, M, 1536, 512,
            (size_t)l * 1536, FLAG);
        attn_kernel<<<nseq * 8, 256, 0, stream>>>(BIG, ATT, L, nseq * 8, BIG, ATT, L);
        gemm_bt<0><<<dim3(4, M / 128), 256, 0, stream>>>(
            ATT, WT_O + (size_t)l * 512 * 512, bo, Y, M, 512, 512,
            (size_t)l * 512, FLAG);
        add_ln_kernel<<<M, 256, 0, stream>>>(X, Y, ln1g, ln1b, (size_t)l * 512, FLAG);
        gemm_bt<1><<<dim3(16, M / 128), 256, 0, stream>>>(
            X, WT_F1 + (size_t)l * 2048 * 512, bff1, BIG, M, 2048, 512,
            (size_t)l * 2048, FLAG);
        gemm_bt<0><<<dim3(4, M / 128), 256, 0, stream>>>(
            BIG, WT_F2 + (size_t)l * 512 * 2048, bff2, Y, M, 512, 2048,
            (size_t)l * 512, FLAG);
        add_ln_kernel<<<M, 256, 0, stream>>>(X, Y, ln2g, ln2b, (size_t)l * 512, FLAG);
      }
      pool_kernel<<<nseq, 256, 0, stream>>>(X, mask, pooled, L, moff, FLAG);
    };
    const int seq_per = 480 / NCH;
    for (int c = 0; c < NCH; c++) {
      encode(fact_ids + (size_t)c * seq_per * 64, seq_per, 64, fact_mask,
             (size_t)c * seq_per * 64, FSEQ + (size_t)c * seq_per * 512);
    }
    encode(hyp_ids, 64, 32, hyp_mask, 0, HSEQ);
  }

  pair_score_kernel<<<16 * 30 * 30, 64, 0, stream>>>(FSEQ, FSEQ, absW, absB, AA, 30, 30, FLAG);
  pair_score_kernel<<<16 * 4 * 30, 64, 0, stream>>>(HSEQ, FSEQ, scoreW, scoreB, QA, 4, 30, FLAG);
  aa_softmax_kernel<<<16, 256, 0, stream>>>(AA, AASM);
  qa_softmax_kernel<<<64, 64, 0, stream>>>(QA, SIM);

  edgew_kernel<<<(16 * 1156 + 255) / 256, 256, 0, stream>>>(
      aa_ov, aa_sim_in, qa_ov, qq, AASM, SIM, p_aaov, p_aasim, p_qaov, p_qasim,
      WMAT, FLAG);
  solve_kernel<<<16, 64, 0, stream>>>(WMAT, PRED, out);
  loss_kernel<<<1, 256, 0, stream>>>(SIM, gold, PRED, labels, out, FLAG);
}